// Round 8
// baseline (957.574 us; speedup 1.0000x reference)
//
#include <hip/hip_runtime.h>

#define B_SZ 4
#define CIN 1024
#define DHI 2048
#define TT 8192
#define KEEP 512
#define OUT_ELEMS (B_SZ*CIN*TT)            // 33554432
#define SPARSE_PER_B (DHI*TT)              // 16777216
#define THRESH 3.0f
#define EPS_SEL 5e-4f
#define BORDER_CAP 64

// A staged bf16 hi/lo image lives in the (not-yet-written) sparse region of
// d_out, overwritten later by zero_sparse. Offset in floats.
#define AST_F ((size_t)OUT_ELEMS)                  // A staged: 8 MB

typedef short bf16x8 __attribute__((ext_vector_type(8)));
typedef float f32x4 __attribute__((ext_vector_type(4)));

__device__ __forceinline__ unsigned short f2bf(float x) {
    unsigned u = __float_as_uint(x);
    return (unsigned short)((u + 0x7fffu + ((u >> 16) & 1u)) >> 16);
}
__device__ __forceinline__ float bf2f(unsigned short h) {
    return __uint_as_float(((unsigned)h) << 16);
}
__device__ __forceinline__ void gload16(const void* g, void* l) {
    __builtin_amdgcn_global_load_lds((const __attribute__((address_space(1))) void*)g,
                                     (__attribute__((address_space(3))) void*)l, 16, 0, 0);
}

// ws layout: counters[0..31] | sel_val[B*512] | sel_idx[B*512] | cand arrays
#define WS_COUNTERS 0
#define WS_SELV 256
#define WS_SELI (256 + 8192)
#define WS_CAND (256 + 16384)

// ---------------- convert A: W_exp [2048][1024] fp32 -> swizzled hi/lo tiles ---
// chunk (DB,KS): 128 rows(d) x 256B: [hi 64k | lo 64k], 16B slot P holds logical
// slot L = P ^ (r&15); L<8: hi octet L; L>=8: lo octet L-8.  (RNE split: A is
// converted once, cold — keep max accuracy here.)
__global__ __launch_bounds__(256) void convert_A(const float* __restrict__ Wexp,
                                                 float* __restrict__ outbuf,
                                                 unsigned* __restrict__ counters) {
    const int DB = blockIdx.x >> 4, KS = blockIdx.x & 15;
    char* dst = (char*)(outbuf + AST_F) + (size_t)blockIdx.x * 32768;
    for (int it = 0; it < 8; ++it) {
        int slot = threadIdx.x + it * 256;      // 0..2047
        int r = slot >> 4, P = slot & 15;
        int L = P ^ (r & 15);
        int part = L >> 3, oct = L & 7;
        const float* src = Wexp + (size_t)(DB * 128 + r) * CIN + KS * 64 + oct * 8;
        unsigned short v[8] __attribute__((aligned(16)));
#pragma unroll
        for (int j = 0; j < 8; ++j) {
            float xv = src[j];
            unsigned short hi = f2bf(xv);
            v[j] = part ? f2bf(xv - bf2f(hi)) : hi;
        }
        *(bf16x8*)(dst + r * 256 + P * 16) = *(const bf16x8*)v;
    }
    if (blockIdx.x == 0 && threadIdx.x < 32) counters[threadIdx.x] = 0u;
}

// ---------------- GEMM: bf16x3 MFMA, fused B conversion, 1-step B prefetch -----
// 128x128 tile, 4 waves x 64x64, BK=64. A via global_load_lds (L2-hot, single
// buffered); B(ks+1) prefetched into 32 regs before MFMA of ks so HBM latency
// hides under compute. Raw s_barrier + counted vmcnt(32) keeps the prefetch in
// flight across the barrier (no compiler vmcnt(0) drain). hi truncated (rem
// exact), lo RNE (zero-mean dropped part -> sqrt(K) error growth, not linear).
__global__ __launch_bounds__(256) void gemm_fused(const float* __restrict__ x,
                                                  const float* __restrict__ stagedA,
                                                  const float* __restrict__ bexp,
                                                  float* __restrict__ cand_val,
                                                  unsigned* __restrict__ cand_idx,
                                                  unsigned* __restrict__ counters,
                                                  int cap) {
    __shared__ char lds[65536];
    __shared__ float s_cv[512];
    __shared__ unsigned s_ci[512];
    __shared__ unsigned s_cnt, s_base;

    const int tid = threadIdx.x;
    const int l = tid & 63, w = tid >> 6;
    const int wm = w >> 1, wn = w & 1;
    const int bx = blockIdx.x, by = blockIdx.y, b = blockIdx.z;

    const char* Achunk0 = (const char*)stagedA + (size_t)(by * 16) * 32768;
    const float* xb = x + (size_t)b * CIN * TT + bx * 128;   // column-block base
    const int t_ = tid & 127;                 // this thread's staging column
    const int L0_ = (tid >> 7) * 4;           // octet base: wave pair 0 -> 0, 1 -> 4
    // per-thread staging tasks: q in 0..3 -> task = tid + q*256 -> L = L0_ + q? No:
    // task>>7 = (tid + q*256)>>7 = (tid>>7) + 2q -> octets interleave; keep exact
    // original mapping below via task arithmetic.

    f32x4 acc[4][4];
#pragma unroll
    for (int i = 0; i < 4; ++i)
#pragma unroll
        for (int j = 0; j < 4; ++j) acc[i][j] = (f32x4)0.f;

    char* ldsA = &lds[0];
    char* ldsB = &lds[32768];

    float breg[32];
    // prologue: load B(ks=0) into regs
#pragma unroll
    for (int q = 0; q < 4; ++q) {
        int task = tid + q * 256;
        int t = task & 127, L = task >> 7;
        const float* src = xb + (size_t)(L * 8) * TT + t;
#pragma unroll
        for (int j = 0; j < 8; ++j) breg[q * 8 + j] = src[(size_t)j * TT];
    }

    for (int ks = 0; ks < 16; ++ks) {
        const int k0 = ks * 64;
        // A staging for current ks: issue first (oldest vm ops; L2-hot)
        {
            const char* gsrcA = Achunk0 + (size_t)ks * 32768 + w * 8192;
            char* ldstA = ldsA + w * 8192;
#pragma unroll
            for (int n = 0; n < 8; ++n)
                gload16(gsrcA + n * 1024 + l * 16, (void*)(ldstA + n * 1024));
        }
        // convert current B regs (compiler inserts counted wait for them),
        // ds_write swizzled; then issue B(ks+1) prefetch.
#pragma unroll
        for (int q = 0; q < 4; ++q) {
            int task = tid + q * 256;            // 0..1023
            int t = task & 127, L = task >> 7;   // L in 0..7
            unsigned short hi[8] __attribute__((aligned(16)));
            unsigned short lo[8] __attribute__((aligned(16)));
#pragma unroll
            for (int j = 0; j < 8; ++j) {
                float xv = breg[q * 8 + j];
                unsigned u = __float_as_uint(xv);
                hi[j] = (unsigned short)(u >> 16);
                float rem = xv - __uint_as_float(u & 0xFFFF0000u);
                unsigned ur = __float_as_uint(rem);
                lo[j] = (unsigned short)((ur + 0x7fffu + ((ur >> 16) & 1u)) >> 16);
            }
            int Ph = L ^ (t & 15), Pl = (L + 8) ^ (t & 15);
            *(bf16x8*)(ldsB + t * 256 + Ph * 16) = *(const bf16x8*)hi;
            *(bf16x8*)(ldsB + t * 256 + Pl * 16) = *(const bf16x8*)lo;
        }
        if (ks < 15) {
#pragma unroll
            for (int q = 0; q < 4; ++q) {
                int task = tid + q * 256;
                int t = task & 127, L = task >> 7;
                const float* src = xb + (size_t)(k0 + 64 + L * 8) * TT + t;
#pragma unroll
                for (int j = 0; j < 8; ++j) breg[q * 8 + j] = src[(size_t)j * TT];
            }
            // wait: 8 A-gloads (older) done, ds_writes done; 32 B prefetch stay in flight
            asm volatile("s_waitcnt vmcnt(32) lgkmcnt(0)" ::: "memory");
        } else {
            asm volatile("s_waitcnt vmcnt(0) lgkmcnt(0)" ::: "memory");
        }
        __builtin_amdgcn_s_barrier();

#pragma unroll
        for (int s = 0; s < 2; ++s) {
            bf16x8 af[4][2], bfr[4][2];
#pragma unroll
            for (int i = 0; i < 4; ++i) {
                int r = wm * 64 + i * 16 + (l & 15);
#pragma unroll
                for (int p = 0; p < 2; ++p) {
                    int L = p * 8 + s * 4 + (l >> 4);
                    int P = L ^ (r & 15);
                    af[i][p] = *(const bf16x8*)(ldsA + r * 256 + P * 16);
                }
            }
#pragma unroll
            for (int j = 0; j < 4; ++j) {
                int r = wn * 64 + j * 16 + (l & 15);
#pragma unroll
                for (int p = 0; p < 2; ++p) {
                    int L = p * 8 + s * 4 + (l >> 4);
                    int P = L ^ (r & 15);
                    bfr[j][p] = *(const bf16x8*)(ldsB + r * 256 + P * 16);
                }
            }
#pragma unroll
            for (int i = 0; i < 4; ++i)
#pragma unroll
                for (int j = 0; j < 4; ++j) {
                    acc[i][j] = __builtin_amdgcn_mfma_f32_16x16x32_bf16(af[i][0], bfr[j][0], acc[i][j], 0, 0, 0);
                    acc[i][j] = __builtin_amdgcn_mfma_f32_16x16x32_bf16(af[i][1], bfr[j][0], acc[i][j], 0, 0, 0);
                    acc[i][j] = __builtin_amdgcn_mfma_f32_16x16x32_bf16(af[i][0], bfr[j][1], acc[i][j], 0, 0, 0);
                }
        }
        __builtin_amdgcn_s_barrier();    // all waves done reading before next writes
    }

    // Epilogue: bias + threshold candidate collection.
    if (tid == 0) s_cnt = 0;
    __syncthreads();
#pragma unroll
    for (int i = 0; i < 4; ++i)
#pragma unroll
        for (int j = 0; j < 4; ++j)
#pragma unroll
            for (int q = 0; q < 4; ++q) {
                int d = by * 128 + wm * 64 + i * 16 + (l >> 4) * 4 + q;
                int t = bx * 128 + wn * 64 + j * 16 + (l & 15);
                float val = acc[i][j][q] + bexp[d];
                if (val > THRESH) {
                    unsigned p = atomicAdd(&s_cnt, 1u);
                    if (p < 512u) {
                        s_cv[p] = val;
                        s_ci[p] = (unsigned)(d * TT + t);
                    }
                }
            }
    __syncthreads();
    unsigned n = s_cnt < 512u ? s_cnt : 512u;
    if (tid == 0) s_base = atomicAdd(&counters[b], n);
    __syncthreads();
    unsigned base = s_base;
    for (unsigned i = tid; i < n; i += 256u) {
        unsigned pos = base + i;
        if (pos < (unsigned)cap) {
            cand_val[(size_t)b * cap + pos] = s_cv[i];
            cand_idx[(size_t)b * cap + pos] = s_ci[i];
        }
    }
}

// ---------------- zero the sparse output region (268 MB) ------------------------
__global__ __launch_bounds__(256) void zero_sparse(float* __restrict__ out) {
    const size_t N4 = (size_t)B_SZ * SPARSE_PER_B / 4;
    float4* o4 = (float4*)(out + (size_t)OUT_ELEMS);
    const float4 z = make_float4(0.f, 0.f, 0.f, 0.f);
    for (size_t i = blockIdx.x * blockDim.x + threadIdx.x; i < N4;
         i += (size_t)gridDim.x * blockDim.x)
        o4[i] = z;
}

// ---------------- merged selection: kth radix + classify + exact border + emit --
__global__ __launch_bounds__(256) void select_all(const float* __restrict__ cand_val,
                                                  const unsigned* __restrict__ cand_idx,
                                                  const unsigned* __restrict__ counters,
                                                  float* __restrict__ sel_val,
                                                  unsigned* __restrict__ sel_idx,
                                                  const float* __restrict__ x,
                                                  const float* __restrict__ Wexp,
                                                  const float* __restrict__ bexp,
                                                  float* __restrict__ d_out,
                                                  int cap) {
    const int b = blockIdx.x;
    const int tid = threadIdx.x;
    const float* cv = cand_val + (size_t)b * cap;
    const unsigned* ci = cand_idx + (size_t)b * cap;
    unsigned nc = counters[b];
    int n = (int)(nc < (unsigned)cap ? nc : (unsigned)cap);

    __shared__ unsigned hist[256];
    __shared__ float red[256];
    __shared__ unsigned s_sel, s_rem, s_scnt, s_bcnt;
    __shared__ float s_bv[BORDER_CAP];
    __shared__ unsigned s_bi[BORDER_CAP];

    for (int i = tid; i < KEEP; i += 256) {
        sel_val[b * KEEP + i] = 0.f;
        sel_idx[b * KEEP + i] = 0u;
    }

    // 4-pass radix: exact 32 bits of the approx rank-512 value (all vals > 3 > 0)
    unsigned prefix = 0;
    int remaining = KEEP;
    for (int pass = 0; pass < 4; ++pass) {
        int shift = 24 - pass * 8;
        hist[tid] = 0;
        __syncthreads();
        for (int i = tid; i < n; i += 256) {
            unsigned u = __float_as_uint(cv[i]);
            unsigned hb = (pass == 0) ? 0u : (u >> (shift + 8));
            if (hb == prefix) atomicAdd(&hist[(u >> shift) & 255u], 1u);
        }
        __syncthreads();
        if (tid == 0) {
            int rem = remaining;
            unsigned selb = 0;
            for (int byte = 255; byte >= 0; --byte) {
                int c = (int)hist[byte];
                if (c >= rem) { selb = (unsigned)byte; break; }
                rem -= c;
            }
            s_sel = selb;
            s_rem = (unsigned)rem;
        }
        __syncthreads();
        prefix = (prefix << 8) | s_sel;
        remaining = (int)s_rem;
        __syncthreads();
    }

    // classify: sure-in emit directly; borderline collect
    if (tid == 0) { s_scnt = 0; s_bcnt = 0; }
    __syncthreads();
    const float kth = __uint_as_float(prefix);
    const float hiv = kth + EPS_SEL, lov = kth - EPS_SEL;
    float* sparse = d_out + (size_t)OUT_ELEMS + (size_t)b * SPARSE_PER_B;
    for (int i = tid; i < n; i += 256) {
        float v = cv[i];
        if (v > hiv) {
            unsigned p = atomicAdd(&s_scnt, 1u);
            unsigned idx = ci[i];
            sel_val[b * KEEP + p] = v;
            sel_idx[b * KEEP + p] = idx;
            sparse[idx] = v;
        } else if (v >= lov) {
            unsigned q = atomicAdd(&s_bcnt, 1u);
            if (q < BORDER_CAP) s_bi[q] = (unsigned)i;
        }
    }
    __syncthreads();
    int nsure = (int)s_scnt;
    int nb = (int)(s_bcnt < BORDER_CAP ? s_bcnt : BORDER_CAP);

    // exact fp32 recompute of borderline candidates (typically 0-2)
    const float* xb = x + (size_t)b * CIN * TT;
    for (int j = 0; j < nb; ++j) {
        unsigned idx = ci[s_bi[j]];
        int d = (int)(idx >> 13), t = (int)(idx & 8191u);
        const float* wr = Wexp + (size_t)d * CIN;
        float ssum = 0.f;
        for (int k = tid; k < CIN; k += 256)
            ssum += xb[(size_t)k * TT + t] * wr[k];
        red[tid] = ssum;
        __syncthreads();
        for (int off = 128; off > 0; off >>= 1) {
            if (tid < off) red[tid] += red[tid + off];
            __syncthreads();
        }
        if (tid == 0) s_bv[j] = red[0] + bexp[d];
        __syncthreads();
    }

    // rank borderline exactly, fill remaining slots
    int r = KEEP - nsure;
    if (r > nb) r = nb;
    if (r < 0) r = 0;
    if (tid < nb) {
        float v = s_bv[tid];
        unsigned idx = ci[s_bi[tid]];
        int rank = 0;
        for (int j = 0; j < nb; ++j) {
            float vj = s_bv[j];
            unsigned ij = ci[s_bi[j]];
            if (vj > v || (vj == v && ij < idx)) rank++;
        }
        if (rank < r) {
            int p = nsure + rank;
            sel_val[b * KEEP + p] = v;
            sel_idx[b * KEEP + p] = idx;
            sparse[idx] = v;
        }
    }
}

// ---------------- fused dense fill + sparse second GEMM -------------------------
// out[b,c,t] = bcon[c] + sum_{j: t_j==t} v_j * Wcon[c][d_j]; pure coalesced write.
__global__ __launch_bounds__(256) void fill_dense(const float* __restrict__ bcon,
                                                  const float* __restrict__ Wcon,
                                                  const float* __restrict__ sel_val,
                                                  const unsigned* __restrict__ sel_idx,
                                                  float* __restrict__ out) {
    const int tcb = blockIdx.x;          // 128 chunks of 64 t
    const int cb  = blockIdx.y;          // 4 chunks of 256 c
    const int b   = blockIdx.z;
    const int tid = threadIdx.x;
    const int t0 = tcb * 64, c0 = cb * 256;

    __shared__ float s_v[BORDER_CAP];
    __shared__ int s_t[BORDER_CAP], s_d[BORDER_CAP];
    __shared__ unsigned s_ne;
    if (tid == 0) s_ne = 0;
    __syncthreads();
    for (int i = tid; i < KEEP; i += 256) {
        float v = sel_val[b * KEEP + i];
        if (v != 0.f) {
            unsigned idx = sel_idx[b * KEEP + i];
            int t = (int)(idx & 8191u);
            if (t >= t0 && t < t0 + 64) {
                unsigned p = atomicAdd(&s_ne, 1u);
                if (p < BORDER_CAP) {
                    s_v[p] = v;
                    s_t[p] = t - t0;
                    s_d[p] = (int)(idx >> 13);
                }
            }
        }
    }
    __syncthreads();
    const int ne = (int)(s_ne < BORDER_CAP ? s_ne : BORDER_CAP);
    const int lane16 = tid & 15;         // t-quad within chunk
    const int cr = tid >> 4;             // 16 c-rows in flight

    for (int it = 0; it < 16; ++it) {
        int c = c0 + it * 16 + cr;
        float bias = bcon[c];
        float v0 = bias, v1 = bias, v2 = bias, v3 = bias;
        for (int j = 0; j < ne; ++j) {
            int tj = s_t[j];
            if ((tj >> 2) == lane16) {
                float add = s_v[j] * Wcon[(size_t)c * DHI + s_d[j]];
                int q = tj & 3;
                if (q == 0) v0 += add;
                else if (q == 1) v1 += add;
                else if (q == 2) v2 += add;
                else v3 += add;
            }
        }
        *(float4*)(&out[(((size_t)(b * CIN + c)) << 13) + t0 + lane16 * 4]) =
            make_float4(v0, v1, v2, v3);
    }
}

extern "C" void kernel_launch(void* const* d_in, const int* in_sizes, int n_in,
                              void* d_out, int out_size, void* d_ws, size_t ws_size,
                              hipStream_t stream) {
    const float* x    = (const float*)d_in[0];
    const float* Wexp = (const float*)d_in[1];
    const float* bexp = (const float*)d_in[2];
    const float* Wcon = (const float*)d_in[3];
    const float* bcon = (const float*)d_in[4];
    float* out = (float*)d_out;

    unsigned* counters = (unsigned*)((char*)d_ws + WS_COUNTERS);
    float*    sel_val  = (float*)((char*)d_ws + WS_SELV);
    unsigned* sel_idx  = (unsigned*)((char*)d_ws + WS_SELI);
    char* cand_base = (char*)d_ws + WS_CAND;
    size_t remain = ws_size - WS_CAND;
    size_t cap_sz = remain / ((size_t)B_SZ * 8);
    int cap = (int)(cap_sz < (size_t)65536 ? cap_sz : (size_t)65536);
    float*    cand_val = (float*)cand_base;
    unsigned* cand_idx = (unsigned*)(cand_base + (size_t)B_SZ * cap * 4);

    // 1) stage split-precision A into d_out's sparse region (8 MB, reused 64x)
    convert_A<<<256, 256, 0, stream>>>(Wexp, out, counters);

    // 2) MFMA bf16x3 GEMM with fused B conversion + 1-step prefetch pipeline
    gemm_fused<<<dim3(64, 16, 4), 256, 0, stream>>>(x, out + AST_F, bexp,
                                                    cand_val, cand_idx, counters, cap);

    // 3) zero sparse output region (A staging dead now)
    zero_sparse<<<2048, 256, 0, stream>>>(out);

    // 4) merged selection: approx kth -> sure emit -> exact borderline -> finalize
    select_all<<<B_SZ, 256, 0, stream>>>(cand_val, cand_idx, counters, sel_val,
                                         sel_idx, x, Wexp, bexp, out, cap);

    // 5) fused dense bias fill + sparse second GEMM (no atomics)
    fill_dense<<<dim3(128, 4, B_SZ), 256, 0, stream>>>(bcon, Wcon, sel_val, sel_idx, out);
}

// Round 9
// 661.274 us; speedup vs baseline: 1.4481x; 1.4481x over previous
//
#include <hip/hip_runtime.h>

#define B_SZ 4
#define CIN 1024
#define DHI 2048
#define TT 8192
#define KEEP 512
#define OUT_ELEMS (B_SZ*CIN*TT)            // 33554432
#define SPARSE_PER_B (DHI*TT)              // 16777216
#define THRESH 3.0f
#define EPS_SEL 5e-4f
#define BORDER_CAP 64

// A staged bf16 hi/lo image lives in the (not-yet-written) sparse region of
// d_out, overwritten later by zero_sparse. Offset in floats.
#define AST_F ((size_t)OUT_ELEMS)                  // A staged: 8 MB

typedef short bf16x8 __attribute__((ext_vector_type(8)));
typedef float f32x4 __attribute__((ext_vector_type(4)));

__device__ __forceinline__ unsigned short f2bf(float x) {
    unsigned u = __float_as_uint(x);
    return (unsigned short)((u + 0x7fffu + ((u >> 16) & 1u)) >> 16);
}
__device__ __forceinline__ float bf2f(unsigned short h) {
    return __uint_as_float(((unsigned)h) << 16);
}
__device__ __forceinline__ void gload16(const void* g, void* l) {
    __builtin_amdgcn_global_load_lds((const __attribute__((address_space(1))) void*)g,
                                     (__attribute__((address_space(3))) void*)l, 16, 0, 0);
}

// ws layout: counters[0..31] | sel_val[B*512] | sel_idx[B*512] | cand arrays
#define WS_COUNTERS 0
#define WS_SELV 256
#define WS_SELI (256 + 8192)
#define WS_CAND (256 + 16384)

// ---------------- convert A: W_exp -> BK=32-native swizzled hi/lo chunks -------
// chunk (DB in 0..15, KS in 0..31): 128 rows(d) x 128B. Row r has 8 16B slots;
// physical slot P holds logical octet L = P ^ (r&7); L<4: hi octet L (k =
// KS*32 + L*8 ..+8); L>=4: lo octet L-4. RNE/RNE split (cold path, max acc).
__global__ __launch_bounds__(256) void convert_A(const float* __restrict__ Wexp,
                                                 float* __restrict__ outbuf,
                                                 unsigned* __restrict__ counters) {
    const int cid = blockIdx.x;             // 512 chunks
    const int DB = cid >> 5, KS = cid & 31;
    char* dst = (char*)(outbuf + AST_F) + (size_t)cid * 16384;
    for (int it = 0; it < 4; ++it) {
        int slot = threadIdx.x + it * 256;  // 0..1023
        int r = slot >> 3, P = slot & 7;
        int L = P ^ (r & 7);
        int part = L >> 2, oct = L & 3;
        const float* src = Wexp + (size_t)(DB * 128 + r) * CIN + KS * 32 + oct * 8;
        unsigned short v[8] __attribute__((aligned(16)));
#pragma unroll
        for (int j = 0; j < 8; ++j) {
            float xv = src[j];
            unsigned short hi = f2bf(xv);
            v[j] = part ? f2bf(xv - bf2f(hi)) : hi;
        }
        *(bf16x8*)(dst + r * 128 + P * 16) = *(const bf16x8*)v;
    }
    if (blockIdx.x == 0 && threadIdx.x < 32) counters[threadIdx.x] = 0u;
}

// ---------------- GEMM: bf16x3 MFMA, fused B conversion, BK=32, 4 blocks/CU ----
// 128x128 tile, 4 waves x 64x64, BK=32. LDS = 16K A + 16K B (+4.3K epilogue)
// -> 4 blocks/CU, 16 waves/CU: cross-block TLP hides B-load latency + barrier
// drains (R6 counters proved the mechanism at 2 blocks; R8 proved its loss at
// 1 block costs 1.5x). hi truncated (rem exact), lo RNE (zero-mean residual).
__global__ __launch_bounds__(256, 4) void gemm_fused(const float* __restrict__ x,
                                                     const float* __restrict__ stagedA,
                                                     const float* __restrict__ bexp,
                                                     float* __restrict__ cand_val,
                                                     unsigned* __restrict__ cand_idx,
                                                     unsigned* __restrict__ counters,
                                                     int cap) {
    __shared__ char lds[32768];
    __shared__ float s_cv[512];
    __shared__ unsigned s_ci[512];
    __shared__ unsigned s_cnt, s_base;

    const int tid = threadIdx.x;
    const int l = tid & 63, w = tid >> 6;
    const int wm = w >> 1, wn = w & 1;
    const int bx = blockIdx.x, by = blockIdx.y, b = blockIdx.z;

    const char* Achunk0 = (const char*)stagedA + (size_t)(by * 32) * 16384;
    const float* xb = x + (size_t)b * CIN * TT + bx * 128;   // column-block base

    f32x4 acc[4][4];
#pragma unroll
    for (int i = 0; i < 4; ++i)
#pragma unroll
        for (int j = 0; j < 4; ++j) acc[i][j] = (f32x4)0.f;

    char* ldsA = &lds[0];
    char* ldsB = &lds[16384];

    for (int ks = 0; ks < 32; ++ks) {
        const int k0 = ks * 32;
        // A staging: async global->LDS, 4 KB per wave (L2-hot staged image)
        {
            const char* gsrcA = Achunk0 + (size_t)ks * 16384 + w * 4096;
            char* ldstA = ldsA + w * 4096;
#pragma unroll
            for (int n = 0; n < 4; ++n)
                gload16(gsrcA + n * 1024 + l * 16, (void*)(ldstA + n * 1024));
        }
        // B staging: read x fp32 (k-strided, wave-coalesced in t), split
        // hi(trunc)/lo(RNE), write swizzled 16B slots. 2 tasks/thread.
#pragma unroll
        for (int q = 0; q < 2; ++q) {
            int task = tid + q * 256;            // 0..511
            int t = task & 127, ko = task >> 7;  // ko in 0..3
            const float* src = xb + (size_t)(k0 + ko * 8) * TT + t;
            float v[8];
#pragma unroll
            for (int j = 0; j < 8; ++j) v[j] = src[(size_t)j * TT];
            unsigned short hi[8] __attribute__((aligned(16)));
            unsigned short lo[8] __attribute__((aligned(16)));
#pragma unroll
            for (int j = 0; j < 8; ++j) {
                unsigned u = __float_as_uint(v[j]);
                hi[j] = (unsigned short)(u >> 16);
                float rem = v[j] - __uint_as_float(u & 0xFFFF0000u);
                unsigned ur = __float_as_uint(rem);
                lo[j] = (unsigned short)((ur + 0x7fffu + ((ur >> 16) & 1u)) >> 16);
            }
            int Ph = ko ^ (t & 7), Pl = (4 + ko) ^ (t & 7);
            *(bf16x8*)(ldsB + t * 128 + Ph * 16) = *(const bf16x8*)hi;
            *(bf16x8*)(ldsB + t * 128 + Pl * 16) = *(const bf16x8*)lo;
        }
        __syncthreads();

        {
            bf16x8 af[4][2], bfr[4][2];
#pragma unroll
            for (int i = 0; i < 4; ++i) {
                int r = wm * 64 + i * 16 + (l & 15);
#pragma unroll
                for (int p = 0; p < 2; ++p) {
                    int L = p * 4 + (l >> 4);
                    int P = L ^ (r & 7);
                    af[i][p] = *(const bf16x8*)(ldsA + r * 128 + P * 16);
                }
            }
#pragma unroll
            for (int j = 0; j < 4; ++j) {
                int r = wn * 64 + j * 16 + (l & 15);
#pragma unroll
                for (int p = 0; p < 2; ++p) {
                    int L = p * 4 + (l >> 4);
                    int P = L ^ (r & 7);
                    bfr[j][p] = *(const bf16x8*)(ldsB + r * 128 + P * 16);
                }
            }
#pragma unroll
            for (int i = 0; i < 4; ++i)
#pragma unroll
                for (int j = 0; j < 4; ++j) {
                    acc[i][j] = __builtin_amdgcn_mfma_f32_16x16x32_bf16(af[i][0], bfr[j][0], acc[i][j], 0, 0, 0);
                    acc[i][j] = __builtin_amdgcn_mfma_f32_16x16x32_bf16(af[i][1], bfr[j][0], acc[i][j], 0, 0, 0);
                    acc[i][j] = __builtin_amdgcn_mfma_f32_16x16x32_bf16(af[i][0], bfr[j][1], acc[i][j], 0, 0, 0);
                }
        }
        __syncthreads();
    }

    // Epilogue: bias + threshold candidate collection.
    if (tid == 0) s_cnt = 0;
    __syncthreads();
#pragma unroll
    for (int i = 0; i < 4; ++i)
#pragma unroll
        for (int j = 0; j < 4; ++j)
#pragma unroll
            for (int q = 0; q < 4; ++q) {
                int d = by * 128 + wm * 64 + i * 16 + (l >> 4) * 4 + q;
                int t = bx * 128 + wn * 64 + j * 16 + (l & 15);
                float val = acc[i][j][q] + bexp[d];
                if (val > THRESH) {
                    unsigned p = atomicAdd(&s_cnt, 1u);
                    if (p < 512u) {
                        s_cv[p] = val;
                        s_ci[p] = (unsigned)(d * TT + t);
                    }
                }
            }
    __syncthreads();
    unsigned n = s_cnt < 512u ? s_cnt : 512u;
    if (tid == 0) s_base = atomicAdd(&counters[b], n);
    __syncthreads();
    unsigned base = s_base;
    for (unsigned i = tid; i < n; i += 256u) {
        unsigned pos = base + i;
        if (pos < (unsigned)cap) {
            cand_val[(size_t)b * cap + pos] = s_cv[i];
            cand_idx[(size_t)b * cap + pos] = s_ci[i];
        }
    }
}

// ---------------- zero the sparse output region (268 MB) ------------------------
__global__ __launch_bounds__(256) void zero_sparse(float* __restrict__ out) {
    const size_t N4 = (size_t)B_SZ * SPARSE_PER_B / 4;
    float4* o4 = (float4*)(out + (size_t)OUT_ELEMS);
    const float4 z = make_float4(0.f, 0.f, 0.f, 0.f);
    for (size_t i = blockIdx.x * blockDim.x + threadIdx.x; i < N4;
         i += (size_t)gridDim.x * blockDim.x)
        o4[i] = z;
}

// ---------------- merged selection: kth radix + classify + exact border + emit --
__global__ __launch_bounds__(256) void select_all(const float* __restrict__ cand_val,
                                                  const unsigned* __restrict__ cand_idx,
                                                  const unsigned* __restrict__ counters,
                                                  float* __restrict__ sel_val,
                                                  unsigned* __restrict__ sel_idx,
                                                  const float* __restrict__ x,
                                                  const float* __restrict__ Wexp,
                                                  const float* __restrict__ bexp,
                                                  float* __restrict__ d_out,
                                                  int cap) {
    const int b = blockIdx.x;
    const int tid = threadIdx.x;
    const float* cv = cand_val + (size_t)b * cap;
    const unsigned* ci = cand_idx + (size_t)b * cap;
    unsigned nc = counters[b];
    int n = (int)(nc < (unsigned)cap ? nc : (unsigned)cap);

    __shared__ unsigned hist[256];
    __shared__ float red[256];
    __shared__ unsigned s_sel, s_rem, s_scnt, s_bcnt;
    __shared__ float s_bv[BORDER_CAP];
    __shared__ unsigned s_bi[BORDER_CAP];

    for (int i = tid; i < KEEP; i += 256) {
        sel_val[b * KEEP + i] = 0.f;
        sel_idx[b * KEEP + i] = 0u;
    }

    // 4-pass radix: exact 32 bits of the approx rank-512 value (all vals > 3 > 0)
    unsigned prefix = 0;
    int remaining = KEEP;
    for (int pass = 0; pass < 4; ++pass) {
        int shift = 24 - pass * 8;
        hist[tid] = 0;
        __syncthreads();
        for (int i = tid; i < n; i += 256) {
            unsigned u = __float_as_uint(cv[i]);
            unsigned hb = (pass == 0) ? 0u : (u >> (shift + 8));
            if (hb == prefix) atomicAdd(&hist[(u >> shift) & 255u], 1u);
        }
        __syncthreads();
        if (tid == 0) {
            int rem = remaining;
            unsigned selb = 0;
            for (int byte = 255; byte >= 0; --byte) {
                int c = (int)hist[byte];
                if (c >= rem) { selb = (unsigned)byte; break; }
                rem -= c;
            }
            s_sel = selb;
            s_rem = (unsigned)rem;
        }
        __syncthreads();
        prefix = (prefix << 8) | s_sel;
        remaining = (int)s_rem;
        __syncthreads();
    }

    // classify: sure-in emit directly; borderline collect
    if (tid == 0) { s_scnt = 0; s_bcnt = 0; }
    __syncthreads();
    const float kth = __uint_as_float(prefix);
    const float hiv = kth + EPS_SEL, lov = kth - EPS_SEL;
    float* sparse = d_out + (size_t)OUT_ELEMS + (size_t)b * SPARSE_PER_B;
    for (int i = tid; i < n; i += 256) {
        float v = cv[i];
        if (v > hiv) {
            unsigned p = atomicAdd(&s_scnt, 1u);
            unsigned idx = ci[i];
            sel_val[b * KEEP + p] = v;
            sel_idx[b * KEEP + p] = idx;
            sparse[idx] = v;
        } else if (v >= lov) {
            unsigned q = atomicAdd(&s_bcnt, 1u);
            if (q < BORDER_CAP) s_bi[q] = (unsigned)i;
        }
    }
    __syncthreads();
    int nsure = (int)s_scnt;
    int nb = (int)(s_bcnt < BORDER_CAP ? s_bcnt : BORDER_CAP);

    // exact fp32 recompute of borderline candidates (typically 0-2)
    const float* xb = x + (size_t)b * CIN * TT;
    for (int j = 0; j < nb; ++j) {
        unsigned idx = ci[s_bi[j]];
        int d = (int)(idx >> 13), t = (int)(idx & 8191u);
        const float* wr = Wexp + (size_t)d * CIN;
        float ssum = 0.f;
        for (int k = tid; k < CIN; k += 256)
            ssum += xb[(size_t)k * TT + t] * wr[k];
        red[tid] = ssum;
        __syncthreads();
        for (int off = 128; off > 0; off >>= 1) {
            if (tid < off) red[tid] += red[tid + off];
            __syncthreads();
        }
        if (tid == 0) s_bv[j] = red[0] + bexp[d];
        __syncthreads();
    }

    // rank borderline exactly, fill remaining slots
    int r = KEEP - nsure;
    if (r > nb) r = nb;
    if (r < 0) r = 0;
    if (tid < nb) {
        float v = s_bv[tid];
        unsigned idx = ci[s_bi[tid]];
        int rank = 0;
        for (int j = 0; j < nb; ++j) {
            float vj = s_bv[j];
            unsigned ij = ci[s_bi[j]];
            if (vj > v || (vj == v && ij < idx)) rank++;
        }
        if (rank < r) {
            int p = nsure + rank;
            sel_val[b * KEEP + p] = v;
            sel_idx[b * KEEP + p] = idx;
            sparse[idx] = v;
        }
    }
}

// ---------------- fused dense fill + sparse second GEMM -------------------------
// out[b,c,t] = bcon[c] + sum_{j: t_j==t} v_j * Wcon[c][d_j]; pure coalesced write.
__global__ __launch_bounds__(256) void fill_dense(const float* __restrict__ bcon,
                                                  const float* __restrict__ Wcon,
                                                  const float* __restrict__ sel_val,
                                                  const unsigned* __restrict__ sel_idx,
                                                  float* __restrict__ out) {
    const int tcb = blockIdx.x;          // 128 chunks of 64 t
    const int cb  = blockIdx.y;          // 4 chunks of 256 c
    const int b   = blockIdx.z;
    const int tid = threadIdx.x;
    const int t0 = tcb * 64, c0 = cb * 256;

    __shared__ float s_v[BORDER_CAP];
    __shared__ int s_t[BORDER_CAP], s_d[BORDER_CAP];
    __shared__ unsigned s_ne;
    if (tid == 0) s_ne = 0;
    __syncthreads();
    for (int i = tid; i < KEEP; i += 256) {
        float v = sel_val[b * KEEP + i];
        if (v != 0.f) {
            unsigned idx = sel_idx[b * KEEP + i];
            int t = (int)(idx & 8191u);
            if (t >= t0 && t < t0 + 64) {
                unsigned p = atomicAdd(&s_ne, 1u);
                if (p < BORDER_CAP) {
                    s_v[p] = v;
                    s_t[p] = t - t0;
                    s_d[p] = (int)(idx >> 13);
                }
            }
        }
    }
    __syncthreads();
    const int ne = (int)(s_ne < BORDER_CAP ? s_ne : BORDER_CAP);
    const int lane16 = tid & 15;         // t-quad within chunk
    const int cr = tid >> 4;             // 16 c-rows in flight

    for (int it = 0; it < 16; ++it) {
        int c = c0 + it * 16 + cr;
        float bias = bcon[c];
        float v0 = bias, v1 = bias, v2 = bias, v3 = bias;
        for (int j = 0; j < ne; ++j) {
            int tj = s_t[j];
            if ((tj >> 2) == lane16) {
                float add = s_v[j] * Wcon[(size_t)c * DHI + s_d[j]];
                int q = tj & 3;
                if (q == 0) v0 += add;
                else if (q == 1) v1 += add;
                else if (q == 2) v2 += add;
                else v3 += add;
            }
        }
        *(float4*)(&out[(((size_t)(b * CIN + c)) << 13) + t0 + lane16 * 4]) =
            make_float4(v0, v1, v2, v3);
    }
}

extern "C" void kernel_launch(void* const* d_in, const int* in_sizes, int n_in,
                              void* d_out, int out_size, void* d_ws, size_t ws_size,
                              hipStream_t stream) {
    const float* x    = (const float*)d_in[0];
    const float* Wexp = (const float*)d_in[1];
    const float* bexp = (const float*)d_in[2];
    const float* Wcon = (const float*)d_in[3];
    const float* bcon = (const float*)d_in[4];
    float* out = (float*)d_out;

    unsigned* counters = (unsigned*)((char*)d_ws + WS_COUNTERS);
    float*    sel_val  = (float*)((char*)d_ws + WS_SELV);
    unsigned* sel_idx  = (unsigned*)((char*)d_ws + WS_SELI);
    char* cand_base = (char*)d_ws + WS_CAND;
    size_t remain = ws_size - WS_CAND;
    size_t cap_sz = remain / ((size_t)B_SZ * 8);
    int cap = (int)(cap_sz < (size_t)65536 ? cap_sz : (size_t)65536);
    float*    cand_val = (float*)cand_base;
    unsigned* cand_idx = (unsigned*)(cand_base + (size_t)B_SZ * cap * 4);

    // 1) stage split-precision A (BK=32-native layout) into d_out's sparse region
    convert_A<<<512, 256, 0, stream>>>(Wexp, out, counters);

    // 2) MFMA bf16x3 GEMM, fused B conversion, BK=32 / 4-blocks-per-CU
    gemm_fused<<<dim3(64, 16, 4), 256, 0, stream>>>(x, out + AST_F, bexp,
                                                    cand_val, cand_idx, counters, cap);

    // 3) zero sparse output region (A staging dead now)
    zero_sparse<<<2048, 256, 0, stream>>>(out);

    // 4) merged selection: approx kth -> sure emit -> exact borderline -> finalize
    select_all<<<B_SZ, 256, 0, stream>>>(cand_val, cand_idx, counters, sel_val,
                                         sel_idx, x, Wexp, bexp, out, cap);

    // 5) fused dense bias fill + sparse second GEMM (no atomics)
    fill_dense<<<dim3(128, 4, B_SZ), 256, 0, stream>>>(bcon, Wcon, sel_val, sel_idx, out);
}

// Round 10
// 621.144 us; speedup vs baseline: 1.5416x; 1.0646x over previous
//
#include <hip/hip_runtime.h>

#define B_SZ 4
#define CIN 1024
#define DHI 2048
#define TT 8192
#define KEEP 512
#define OUT_ELEMS (B_SZ*CIN*TT)            // 33554432
#define SPARSE_PER_B (DHI*TT)              // 16777216
#define THRESH 3.0f
#define EPS_SEL 5e-4f
#define BORDER_CAP 64
#define FILL_CAP 128

// A staged bf16 hi/lo image lives in the (not-yet-written) sparse region of
// d_out; fill_all (which runs after the gemm) overwrites it with zeros.
#define AST_F ((size_t)OUT_ELEMS)                  // A staged: 8 MB

typedef short bf16x8 __attribute__((ext_vector_type(8)));
typedef float f32x4 __attribute__((ext_vector_type(4)));

__device__ __forceinline__ unsigned short f2bf(float x) {
    unsigned u = __float_as_uint(x);
    return (unsigned short)((u + 0x7fffu + ((u >> 16) & 1u)) >> 16);
}
__device__ __forceinline__ float bf2f(unsigned short h) {
    return __uint_as_float(((unsigned)h) << 16);
}
__device__ __forceinline__ void gload16(const void* g, void* l) {
    __builtin_amdgcn_global_load_lds((const __attribute__((address_space(1))) void*)g,
                                     (__attribute__((address_space(3))) void*)l, 16, 0, 0);
}

// ws layout: counters[0..31] | sel_val[B*512] | sel_idx[B*512] | cand arrays
#define WS_COUNTERS 0
#define WS_SELV 256
#define WS_SELI (256 + 8192)
#define WS_CAND (256 + 16384)

// ---------------- convert A: W_exp -> BK=32-native swizzled hi/lo chunks -------
// chunk (DB in 0..15, KS in 0..31): 128 rows(d) x 128B. Row r has 8 16B slots;
// physical slot P holds logical octet L = P ^ (r&7); L<4: hi octet L (k =
// KS*32 + L*8 ..+8); L>=4: lo octet L-4. RNE/RNE split (cold path, max acc).
__global__ __launch_bounds__(256) void convert_A(const float* __restrict__ Wexp,
                                                 float* __restrict__ outbuf,
                                                 unsigned* __restrict__ counters) {
    const int cid = blockIdx.x;             // 512 chunks
    const int DB = cid >> 5, KS = cid & 31;
    char* dst = (char*)(outbuf + AST_F) + (size_t)cid * 16384;
    for (int it = 0; it < 4; ++it) {
        int slot = threadIdx.x + it * 256;  // 0..1023
        int r = slot >> 3, P = slot & 7;
        int L = P ^ (r & 7);
        int part = L >> 2, oct = L & 3;
        const float* src = Wexp + (size_t)(DB * 128 + r) * CIN + KS * 32 + oct * 8;
        unsigned short v[8] __attribute__((aligned(16)));
#pragma unroll
        for (int j = 0; j < 8; ++j) {
            float xv = src[j];
            unsigned short hi = f2bf(xv);
            v[j] = part ? f2bf(xv - bf2f(hi)) : hi;
        }
        *(bf16x8*)(dst + r * 128 + P * 16) = *(const bf16x8*)v;
    }
    if (blockIdx.x == 0 && threadIdx.x < 32) counters[threadIdx.x] = 0u;
}

// ---------------- GEMM: bf16x3 MFMA, fused B conversion, BK=32, 4 blocks/CU ----
// (byte-identical to R9's verified kernel: VGPR 64, 4 blocks/CU, MfmaUtil ~55%
// = at the 412-GFLOP bf16x3 floor for the 16x16 shape)
__global__ __launch_bounds__(256, 4) void gemm_fused(const float* __restrict__ x,
                                                     const float* __restrict__ stagedA,
                                                     const float* __restrict__ bexp,
                                                     float* __restrict__ cand_val,
                                                     unsigned* __restrict__ cand_idx,
                                                     unsigned* __restrict__ counters,
                                                     int cap) {
    __shared__ char lds[32768];
    __shared__ float s_cv[512];
    __shared__ unsigned s_ci[512];
    __shared__ unsigned s_cnt, s_base;

    const int tid = threadIdx.x;
    const int l = tid & 63, w = tid >> 6;
    const int wm = w >> 1, wn = w & 1;
    const int bx = blockIdx.x, by = blockIdx.y, b = blockIdx.z;

    const char* Achunk0 = (const char*)stagedA + (size_t)(by * 32) * 16384;
    const float* xb = x + (size_t)b * CIN * TT + bx * 128;   // column-block base

    f32x4 acc[4][4];
#pragma unroll
    for (int i = 0; i < 4; ++i)
#pragma unroll
        for (int j = 0; j < 4; ++j) acc[i][j] = (f32x4)0.f;

    char* ldsA = &lds[0];
    char* ldsB = &lds[16384];

    for (int ks = 0; ks < 32; ++ks) {
        const int k0 = ks * 32;
        // A staging: async global->LDS, 4 KB per wave (L2-hot staged image)
        {
            const char* gsrcA = Achunk0 + (size_t)ks * 16384 + w * 4096;
            char* ldstA = ldsA + w * 4096;
#pragma unroll
            for (int n = 0; n < 4; ++n)
                gload16(gsrcA + n * 1024 + l * 16, (void*)(ldstA + n * 1024));
        }
        // B staging: read x fp32 (k-strided, wave-coalesced in t), split
        // hi(trunc)/lo(RNE), write swizzled 16B slots. 2 tasks/thread.
#pragma unroll
        for (int q = 0; q < 2; ++q) {
            int task = tid + q * 256;            // 0..511
            int t = task & 127, ko = task >> 7;  // ko in 0..3
            const float* src = xb + (size_t)(k0 + ko * 8) * TT + t;
            float v[8];
#pragma unroll
            for (int j = 0; j < 8; ++j) v[j] = src[(size_t)j * TT];
            unsigned short hi[8] __attribute__((aligned(16)));
            unsigned short lo[8] __attribute__((aligned(16)));
#pragma unroll
            for (int j = 0; j < 8; ++j) {
                unsigned u = __float_as_uint(v[j]);
                hi[j] = (unsigned short)(u >> 16);
                float rem = v[j] - __uint_as_float(u & 0xFFFF0000u);
                unsigned ur = __float_as_uint(rem);
                lo[j] = (unsigned short)((ur + 0x7fffu + ((ur >> 16) & 1u)) >> 16);
            }
            int Ph = ko ^ (t & 7), Pl = (4 + ko) ^ (t & 7);
            *(bf16x8*)(ldsB + t * 128 + Ph * 16) = *(const bf16x8*)hi;
            *(bf16x8*)(ldsB + t * 128 + Pl * 16) = *(const bf16x8*)lo;
        }
        __syncthreads();

        {
            bf16x8 af[4][2], bfr[4][2];
#pragma unroll
            for (int i = 0; i < 4; ++i) {
                int r = wm * 64 + i * 16 + (l & 15);
#pragma unroll
                for (int p = 0; p < 2; ++p) {
                    int L = p * 4 + (l >> 4);
                    int P = L ^ (r & 7);
                    af[i][p] = *(const bf16x8*)(ldsA + r * 128 + P * 16);
                }
            }
#pragma unroll
            for (int j = 0; j < 4; ++j) {
                int r = wn * 64 + j * 16 + (l & 15);
#pragma unroll
                for (int p = 0; p < 2; ++p) {
                    int L = p * 4 + (l >> 4);
                    int P = L ^ (r & 7);
                    bfr[j][p] = *(const bf16x8*)(ldsB + r * 128 + P * 16);
                }
            }
#pragma unroll
            for (int i = 0; i < 4; ++i)
#pragma unroll
                for (int j = 0; j < 4; ++j) {
                    acc[i][j] = __builtin_amdgcn_mfma_f32_16x16x32_bf16(af[i][0], bfr[j][0], acc[i][j], 0, 0, 0);
                    acc[i][j] = __builtin_amdgcn_mfma_f32_16x16x32_bf16(af[i][1], bfr[j][0], acc[i][j], 0, 0, 0);
                    acc[i][j] = __builtin_amdgcn_mfma_f32_16x16x32_bf16(af[i][0], bfr[j][1], acc[i][j], 0, 0, 0);
                }
        }
        __syncthreads();
    }

    // Epilogue: bias + threshold candidate collection.
    if (tid == 0) s_cnt = 0;
    __syncthreads();
#pragma unroll
    for (int i = 0; i < 4; ++i)
#pragma unroll
        for (int j = 0; j < 4; ++j)
#pragma unroll
            for (int q = 0; q < 4; ++q) {
                int d = by * 128 + wm * 64 + i * 16 + (l >> 4) * 4 + q;
                int t = bx * 128 + wn * 64 + j * 16 + (l & 15);
                float val = acc[i][j][q] + bexp[d];
                if (val > THRESH) {
                    unsigned p = atomicAdd(&s_cnt, 1u);
                    if (p < 512u) {
                        s_cv[p] = val;
                        s_ci[p] = (unsigned)(d * TT + t);
                    }
                }
            }
    __syncthreads();
    unsigned n = s_cnt < 512u ? s_cnt : 512u;
    if (tid == 0) s_base = atomicAdd(&counters[b], n);
    __syncthreads();
    unsigned base = s_base;
    for (unsigned i = tid; i < n; i += 256u) {
        unsigned pos = base + i;
        if (pos < (unsigned)cap) {
            cand_val[(size_t)b * cap + pos] = s_cv[i];
            cand_idx[(size_t)b * cap + pos] = s_ci[i];
        }
    }
}

// ---------------- merged selection: kth radix + classify + exact border --------
// Builds sel_val/sel_idx only; all output writing moved to fill_all.
__global__ __launch_bounds__(256) void select_all(const float* __restrict__ cand_val,
                                                  const unsigned* __restrict__ cand_idx,
                                                  const unsigned* __restrict__ counters,
                                                  float* __restrict__ sel_val,
                                                  unsigned* __restrict__ sel_idx,
                                                  const float* __restrict__ x,
                                                  const float* __restrict__ Wexp,
                                                  const float* __restrict__ bexp,
                                                  int cap) {
    const int b = blockIdx.x;
    const int tid = threadIdx.x;
    const float* cv = cand_val + (size_t)b * cap;
    const unsigned* ci = cand_idx + (size_t)b * cap;
    unsigned nc = counters[b];
    int n = (int)(nc < (unsigned)cap ? nc : (unsigned)cap);

    __shared__ unsigned hist[256];
    __shared__ float red[256];
    __shared__ unsigned s_sel, s_rem, s_scnt, s_bcnt;
    __shared__ float s_bv[BORDER_CAP];
    __shared__ unsigned s_bi[BORDER_CAP];

    for (int i = tid; i < KEEP; i += 256) {
        sel_val[b * KEEP + i] = 0.f;
        sel_idx[b * KEEP + i] = 0u;
    }

    // 4-pass radix: exact 32 bits of the approx rank-512 value (all vals > 3 > 0)
    unsigned prefix = 0;
    int remaining = KEEP;
    for (int pass = 0; pass < 4; ++pass) {
        int shift = 24 - pass * 8;
        hist[tid] = 0;
        __syncthreads();
        for (int i = tid; i < n; i += 256) {
            unsigned u = __float_as_uint(cv[i]);
            unsigned hb = (pass == 0) ? 0u : (u >> (shift + 8));
            if (hb == prefix) atomicAdd(&hist[(u >> shift) & 255u], 1u);
        }
        __syncthreads();
        if (tid == 0) {
            int rem = remaining;
            unsigned selb = 0;
            for (int byte = 255; byte >= 0; --byte) {
                int c = (int)hist[byte];
                if (c >= rem) { selb = (unsigned)byte; break; }
                rem -= c;
            }
            s_sel = selb;
            s_rem = (unsigned)rem;
        }
        __syncthreads();
        prefix = (prefix << 8) | s_sel;
        remaining = (int)s_rem;
        __syncthreads();
    }

    // classify: sure-in emit to sel arrays; borderline collect
    if (tid == 0) { s_scnt = 0; s_bcnt = 0; }
    __syncthreads();
    const float kth = __uint_as_float(prefix);
    const float hiv = kth + EPS_SEL, lov = kth - EPS_SEL;
    for (int i = tid; i < n; i += 256) {
        float v = cv[i];
        if (v > hiv) {
            unsigned p = atomicAdd(&s_scnt, 1u);
            sel_val[b * KEEP + p] = v;
            sel_idx[b * KEEP + p] = ci[i];
        } else if (v >= lov) {
            unsigned q = atomicAdd(&s_bcnt, 1u);
            if (q < BORDER_CAP) s_bi[q] = (unsigned)i;
        }
    }
    __syncthreads();
    int nsure = (int)s_scnt;
    int nb = (int)(s_bcnt < BORDER_CAP ? s_bcnt : BORDER_CAP);

    // exact fp32 recompute of borderline candidates (typically 0-2)
    const float* xb = x + (size_t)b * CIN * TT;
    for (int j = 0; j < nb; ++j) {
        unsigned idx = ci[s_bi[j]];
        int d = (int)(idx >> 13), t = (int)(idx & 8191u);
        const float* wr = Wexp + (size_t)d * CIN;
        float ssum = 0.f;
        for (int k = tid; k < CIN; k += 256)
            ssum += xb[(size_t)k * TT + t] * wr[k];
        red[tid] = ssum;
        __syncthreads();
        for (int off = 128; off > 0; off >>= 1) {
            if (tid < off) red[tid] += red[tid + off];
            __syncthreads();
        }
        if (tid == 0) s_bv[j] = red[0] + bexp[d];
        __syncthreads();
    }

    // rank borderline exactly, fill remaining slots
    int r = KEEP - nsure;
    if (r > nb) r = nb;
    if (r < 0) r = 0;
    if (tid < nb) {
        float v = s_bv[tid];
        unsigned idx = ci[s_bi[tid]];
        int rank = 0;
        for (int j = 0; j < nb; ++j) {
            float vj = s_bv[j];
            unsigned ij = ci[s_bi[j]];
            if (vj > v || (vj == v && ij < idx)) rank++;
        }
        if (rank < r) {
            int p = nsure + rank;
            sel_val[b * KEEP + p] = v;
            sel_idx[b * KEEP + p] = idx;
        }
    }
}

// ---------------- fill_all: ALL output writes in one pass -----------------------
// grid (128 t-chunks, 12 = 4 dense c-chunks + 8 sparse d-chunks, B).
// dense: out[b,c,t] = bcon[c] + sum_{j: t_j==t} v_j * Wcon[c][d_j]
// sparse: zeros everywhere, patch the <=512 selected (d,t) with their values.
// Runs after gemm, so it safely overwrites the A-staging bytes with zeros.
__global__ __launch_bounds__(256) void fill_all(const float* __restrict__ bcon,
                                                const float* __restrict__ Wcon,
                                                const float* __restrict__ sel_val,
                                                const unsigned* __restrict__ sel_idx,
                                                float* __restrict__ out) {
    const int tcb = blockIdx.x;          // 128 chunks of 64 t
    const int yc  = blockIdx.y;          // 0..3 dense, 4..11 sparse
    const int b   = blockIdx.z;
    const int tid = threadIdx.x;
    const int t0 = tcb * 64;

    __shared__ float s_v[FILL_CAP];
    __shared__ int s_t[FILL_CAP], s_d[FILL_CAP];
    __shared__ unsigned s_ne;
    if (tid == 0) s_ne = 0;
    __syncthreads();

    if (yc < 4) {
        const int c0 = yc * 256;
        for (int i = tid; i < KEEP; i += 256) {
            float v = sel_val[b * KEEP + i];
            if (v != 0.f) {
                unsigned idx = sel_idx[b * KEEP + i];
                int t = (int)(idx & 8191u);
                if (t >= t0 && t < t0 + 64) {
                    unsigned p = atomicAdd(&s_ne, 1u);
                    if (p < FILL_CAP) {
                        s_v[p] = v;
                        s_t[p] = t - t0;
                        s_d[p] = (int)(idx >> 13);
                    }
                }
            }
        }
        __syncthreads();
        const int ne = (int)(s_ne < FILL_CAP ? s_ne : FILL_CAP);
        const int lane16 = tid & 15;     // t-quad within chunk
        const int cr = tid >> 4;         // 16 c-rows in flight
        for (int it = 0; it < 16; ++it) {
            int c = c0 + it * 16 + cr;
            float bias = bcon[c];
            float v0 = bias, v1 = bias, v2 = bias, v3 = bias;
            for (int j = 0; j < ne; ++j) {
                int tj = s_t[j];
                if ((tj >> 2) == lane16) {
                    float add = s_v[j] * Wcon[(size_t)c * DHI + s_d[j]];
                    int q = tj & 3;
                    if (q == 0) v0 += add;
                    else if (q == 1) v1 += add;
                    else if (q == 2) v2 += add;
                    else v3 += add;
                }
            }
            *(float4*)(&out[(((size_t)(b * CIN + c)) << 13) + t0 + lane16 * 4]) =
                make_float4(v0, v1, v2, v3);
        }
    } else {
        const int d0 = (yc - 4) * 256;
        float* sparse = out + (size_t)OUT_ELEMS + (size_t)b * SPARSE_PER_B;
        for (int i = tid; i < KEEP; i += 256) {
            float v = sel_val[b * KEEP + i];
            if (v != 0.f) {
                unsigned idx = sel_idx[b * KEEP + i];
                int t = (int)(idx & 8191u), d = (int)(idx >> 13);
                if (t >= t0 && t < t0 + 64 && d >= d0 && d < d0 + 256) {
                    unsigned p = atomicAdd(&s_ne, 1u);
                    if (p < FILL_CAP) {
                        s_v[p] = v;
                        s_t[p] = t;
                        s_d[p] = d;
                    }
                }
            }
        }
        __syncthreads();
        const int ne = (int)(s_ne < FILL_CAP ? s_ne : FILL_CAP);
        const int lane16 = tid & 15;
        const int dr = tid >> 4;
        const float4 z = make_float4(0.f, 0.f, 0.f, 0.f);
        for (int it = 0; it < 16; ++it) {
            int d = d0 + it * 16 + dr;
            *(float4*)(&sparse[((size_t)d << 13) + t0 + lane16 * 4]) = z;
        }
        __syncthreads();                 // zeros visible before patch
        if (tid < ne)
            sparse[((size_t)s_d[tid] << 13) + s_t[tid]] = s_v[tid];
    }
}

extern "C" void kernel_launch(void* const* d_in, const int* in_sizes, int n_in,
                              void* d_out, int out_size, void* d_ws, size_t ws_size,
                              hipStream_t stream) {
    const float* x    = (const float*)d_in[0];
    const float* Wexp = (const float*)d_in[1];
    const float* bexp = (const float*)d_in[2];
    const float* Wcon = (const float*)d_in[3];
    const float* bcon = (const float*)d_in[4];
    float* out = (float*)d_out;

    unsigned* counters = (unsigned*)((char*)d_ws + WS_COUNTERS);
    float*    sel_val  = (float*)((char*)d_ws + WS_SELV);
    unsigned* sel_idx  = (unsigned*)((char*)d_ws + WS_SELI);
    char* cand_base = (char*)d_ws + WS_CAND;
    size_t remain = ws_size - WS_CAND;
    size_t cap_sz = remain / ((size_t)B_SZ * 8);
    int cap = (int)(cap_sz < (size_t)65536 ? cap_sz : (size_t)65536);
    float*    cand_val = (float*)cand_base;
    unsigned* cand_idx = (unsigned*)(cand_base + (size_t)B_SZ * cap * 4);

    // 1) stage split-precision A (BK=32-native layout) into d_out's sparse region
    convert_A<<<512, 256, 0, stream>>>(Wexp, out, counters);

    // 2) MFMA bf16x3 GEMM, fused B conversion, BK=32 / 4-blocks-per-CU
    gemm_fused<<<dim3(64, 16, 4), 256, 0, stream>>>(x, out + AST_F, bexp,
                                                    cand_val, cand_idx, counters, cap);

    // 3) selection: approx kth -> sure emit -> exact borderline -> sel arrays
    select_all<<<B_SZ, 256, 0, stream>>>(cand_val, cand_idx, counters, sel_val,
                                         sel_idx, x, Wexp, bexp, cap);

    // 4) single output pass: dense bias+scatter-GEMM, sparse zeros+patch
    fill_all<<<dim3(128, 12, B_SZ), 256, 0, stream>>>(bcon, Wcon, sel_val, sel_idx, out);
}

// Round 11
// 599.851 us; speedup vs baseline: 1.5964x; 1.0355x over previous
//
#include <hip/hip_runtime.h>

#define B_SZ 4
#define CIN 1024
#define DHI 2048
#define TT 8192
#define KEEP 512
#define OUT_ELEMS (B_SZ*CIN*TT)            // 33554432
#define SPARSE_PER_B (DHI*TT)              // 16777216
#define THRESH 3.0f
#define EPS_SEL 0.04f
#define BORDER_CAP 256
#define FILL_CAP 128

// A staged bf16-hi image lives in the (not-yet-written) sparse region of
// d_out; fill_all (after the gemm) overwrites it with zeros. 4 MB.
#define AST_F ((size_t)OUT_ELEMS)

typedef short bf16x8 __attribute__((ext_vector_type(8)));
typedef float f32x4 __attribute__((ext_vector_type(4)));

__device__ __forceinline__ unsigned short f2bf(float x) {
    unsigned u = __float_as_uint(x);
    return (unsigned short)((u + 0x7fffu + ((u >> 16) & 1u)) >> 16);
}
__device__ __forceinline__ void gload16(const void* g, void* l) {
    __builtin_amdgcn_global_load_lds((const __attribute__((address_space(1))) void*)g,
                                     (__attribute__((address_space(3))) void*)l, 16, 0, 0);
}

// ws: counters[32] | sel_val[4*512] | sel_idx[4*512] | border_idx[4*256] |
//     border_val[4*256] | cand arrays
#define WS_COUNTERS 0
#define WS_SELV 256
#define WS_SELI (256 + 8192)
#define WS_BIDX (256 + 16384)
#define WS_BVAL (256 + 16384 + 4096)
#define WS_CAND (256 + 16384 + 8192)
// counters: [b]=cand cnt, [4+b]=nsure, [8+b]=nborder

// ---------------- convert A: W_exp -> BK=32-native swizzled HI-ONLY chunks -----
// chunk (DB 0..15, KS 0..31): 128 rows(d) x 64B (4 slots x 16B). Physical slot
// P holds logical octet L = P ^ (r&3); k = KS*32 + L*8 .. +8. RNE (cold path).
__global__ __launch_bounds__(256) void convert_A(const float* __restrict__ Wexp,
                                                 float* __restrict__ outbuf,
                                                 unsigned* __restrict__ counters) {
    const int cid = blockIdx.x;             // 512 chunks x 8KB = 4MB
    const int DB = cid >> 5, KS = cid & 31;
    char* dst = (char*)(outbuf + AST_F) + (size_t)cid * 8192;
    for (int it = 0; it < 2; ++it) {
        int slot = threadIdx.x + it * 256;  // 0..511
        int r = slot >> 2, P = slot & 3;
        int L = P ^ (r & 3);
        const float* src = Wexp + (size_t)(DB * 128 + r) * CIN + KS * 32 + L * 8;
        unsigned short v[8] __attribute__((aligned(16)));
#pragma unroll
        for (int j = 0; j < 8; ++j) v[j] = f2bf(src[j]);
        *(bf16x8*)(dst + r * 64 + P * 16) = *(const bf16x8*)v;
    }
    if (blockIdx.x == 0 && threadIdx.x < 32) counters[threadIdx.x] = 0u;
}

// ---------------- GEMM: SINGLE bf16 product (Ahi*Bhi), BK=32 -------------------
// 128x128 tile, 4 waves x 64x64. Approximation error sigma ~2.3e-3 (max ~0.013
// over all candidates) — selection correctness restored by EPS_SEL window +
// exact fp32 recompute of all sure+borderline entries (select1/recompute).
// LDS 20.5KB -> 6-7 blocks/CU for cross-block latency hiding (R9 mechanism).
__global__ __launch_bounds__(256, 4) void gemm_fused(const float* __restrict__ x,
                                                     const float* __restrict__ stagedA,
                                                     const float* __restrict__ bexp,
                                                     float* __restrict__ cand_val,
                                                     unsigned* __restrict__ cand_idx,
                                                     unsigned* __restrict__ counters,
                                                     int cap) {
    __shared__ char lds[16384];
    __shared__ float s_cv[512];
    __shared__ unsigned s_ci[512];
    __shared__ unsigned s_cnt, s_base;

    const int tid = threadIdx.x;
    const int l = tid & 63, w = tid >> 6;
    const int wm = w >> 1, wn = w & 1;
    const int bx = blockIdx.x, by = blockIdx.y, b = blockIdx.z;

    const char* Achunk0 = (const char*)stagedA + (size_t)(by * 32) * 8192;
    const float* xb = x + (size_t)b * CIN * TT + bx * 128;

    f32x4 acc[4][4];
#pragma unroll
    for (int i = 0; i < 4; ++i)
#pragma unroll
        for (int j = 0; j < 4; ++j) acc[i][j] = (f32x4)0.f;

    char* ldsA = &lds[0];
    char* ldsB = &lds[8192];

    for (int ks = 0; ks < 32; ++ks) {
        const int k0 = ks * 32;
        // A staging: async global->LDS, 2KB per wave (L2-hot staged image)
        {
            const char* gsrcA = Achunk0 + (size_t)ks * 8192 + w * 2048;
            char* ldstA = ldsA + w * 2048;
            gload16(gsrcA + l * 16, (void*)ldstA);
            gload16(gsrcA + 1024 + l * 16, (void*)(ldstA + 1024));
        }
        // B staging: read x fp32 (k-strided, wave-coalesced in t), TRUNCATE to
        // bf16 hi, write swizzled 16B slots. 2 tasks/thread.
#pragma unroll
        for (int q = 0; q < 2; ++q) {
            int task = tid + q * 256;            // 0..511
            int t = task & 127, ko = task >> 7;  // ko in 0..3
            const float* src = xb + (size_t)(k0 + ko * 8) * TT + t;
            unsigned short hi[8] __attribute__((aligned(16)));
#pragma unroll
            for (int j = 0; j < 8; ++j)
                hi[j] = (unsigned short)(__float_as_uint(src[(size_t)j * TT]) >> 16);
            int Ph = ko ^ (t & 3);
            *(bf16x8*)(ldsB + t * 64 + Ph * 16) = *(const bf16x8*)hi;
        }
        __syncthreads();

        {
            bf16x8 af[4], bfr[4];
#pragma unroll
            for (int i = 0; i < 4; ++i) {
                int r = wm * 64 + i * 16 + (l & 15);
                int P = (l >> 4) ^ (r & 3);
                af[i] = *(const bf16x8*)(ldsA + r * 64 + P * 16);
            }
#pragma unroll
            for (int j = 0; j < 4; ++j) {
                int r = wn * 64 + j * 16 + (l & 15);
                int P = (l >> 4) ^ (r & 3);
                bfr[j] = *(const bf16x8*)(ldsB + r * 64 + P * 16);
            }
#pragma unroll
            for (int i = 0; i < 4; ++i)
#pragma unroll
                for (int j = 0; j < 4; ++j)
                    acc[i][j] = __builtin_amdgcn_mfma_f32_16x16x32_bf16(af[i], bfr[j], acc[i][j], 0, 0, 0);
        }
        __syncthreads();
    }

    // Epilogue: bias + threshold candidate collection (approx values).
    if (tid == 0) s_cnt = 0;
    __syncthreads();
#pragma unroll
    for (int i = 0; i < 4; ++i)
#pragma unroll
        for (int j = 0; j < 4; ++j)
#pragma unroll
            for (int q = 0; q < 4; ++q) {
                int d = by * 128 + wm * 64 + i * 16 + (l >> 4) * 4 + q;
                int t = bx * 128 + wn * 64 + j * 16 + (l & 15);
                float val = acc[i][j][q] + bexp[d];
                if (val > THRESH) {
                    unsigned p = atomicAdd(&s_cnt, 1u);
                    if (p < 512u) {
                        s_cv[p] = val;
                        s_ci[p] = (unsigned)(d * TT + t);
                    }
                }
            }
    __syncthreads();
    unsigned n = s_cnt < 512u ? s_cnt : 512u;
    if (tid == 0) s_base = atomicAdd(&counters[b], n);
    __syncthreads();
    unsigned base = s_base;
    for (unsigned i = tid; i < n; i += 256u) {
        unsigned pos = base + i;
        if (pos < (unsigned)cap) {
            cand_val[(size_t)b * cap + pos] = s_cv[i];
            cand_idx[(size_t)b * cap + pos] = s_ci[i];
        }
    }
}

// ---------------- select1: radix kth on approx values + classify ---------------
// sure (v > kth+EPS): index into sel_idx (value filled by recompute).
// borderline (kth-EPS <= v <= kth+EPS): index into border list.
__global__ __launch_bounds__(256) void select1(const float* __restrict__ cand_val,
                                               const unsigned* __restrict__ cand_idx,
                                               unsigned* __restrict__ counters,
                                               float* __restrict__ sel_val,
                                               unsigned* __restrict__ sel_idx,
                                               unsigned* __restrict__ border_idx,
                                               int cap) {
    const int b = blockIdx.x;
    const int tid = threadIdx.x;
    const float* cv = cand_val + (size_t)b * cap;
    const unsigned* ci = cand_idx + (size_t)b * cap;
    unsigned nc = counters[b];
    int n = (int)(nc < (unsigned)cap ? nc : (unsigned)cap);

    __shared__ unsigned hist[256];
    __shared__ unsigned s_sel, s_rem, s_scnt, s_bcnt;

    for (int i = tid; i < KEEP; i += 256) {
        sel_val[b * KEEP + i] = 0.f;
        sel_idx[b * KEEP + i] = 0u;
    }

    unsigned prefix = 0;
    int remaining = KEEP;
    for (int pass = 0; pass < 4; ++pass) {
        int shift = 24 - pass * 8;
        hist[tid] = 0;
        __syncthreads();
        for (int i = tid; i < n; i += 256) {
            unsigned u = __float_as_uint(cv[i]);
            unsigned hb = (pass == 0) ? 0u : (u >> (shift + 8));
            if (hb == prefix) atomicAdd(&hist[(u >> shift) & 255u], 1u);
        }
        __syncthreads();
        if (tid == 0) {
            int rem = remaining;
            unsigned selb = 0;
            for (int byte = 255; byte >= 0; --byte) {
                int c = (int)hist[byte];
                if (c >= rem) { selb = (unsigned)byte; break; }
                rem -= c;
            }
            s_sel = selb;
            s_rem = (unsigned)rem;
        }
        __syncthreads();
        prefix = (prefix << 8) | s_sel;
        remaining = (int)s_rem;
        __syncthreads();
    }

    if (tid == 0) { s_scnt = 0; s_bcnt = 0; }
    __syncthreads();
    const float kth = __uint_as_float(prefix);
    const float hiv = kth + EPS_SEL, lov = kth - EPS_SEL;
    for (int i = tid; i < n; i += 256) {
        float v = cv[i];
        if (v > hiv) {
            unsigned p = atomicAdd(&s_scnt, 1u);
            if (p < (unsigned)KEEP) sel_idx[b * KEEP + p] = ci[i];
        } else if (v >= lov) {
            unsigned q = atomicAdd(&s_bcnt, 1u);
            if (q < BORDER_CAP) border_idx[b * BORDER_CAP + q] = ci[i];
        }
    }
    __syncthreads();
    if (tid == 0) {
        counters[4 + b] = s_scnt < (unsigned)KEEP ? s_scnt : (unsigned)KEEP;
        counters[8 + b] = s_bcnt < BORDER_CAP ? s_bcnt : BORDER_CAP;
    }
}

// ---------------- recompute: exact fp32 dot for every sure + borderline entry --
__global__ __launch_bounds__(256) void recompute(const float* __restrict__ x,
                                                 const float* __restrict__ Wexp,
                                                 const float* __restrict__ bexp,
                                                 const unsigned* __restrict__ counters,
                                                 const unsigned* __restrict__ sel_idx,
                                                 float* __restrict__ sel_val,
                                                 const unsigned* __restrict__ border_idx,
                                                 float* __restrict__ border_val) {
    const int j = blockIdx.x, b = blockIdx.y;
    const int nsure = (int)counters[4 + b];
    const int nb = (int)counters[8 + b];
    unsigned idx;
    float* dst;
    if (j < KEEP) {
        if (j >= nsure) return;
        idx = sel_idx[b * KEEP + j];
        dst = &sel_val[b * KEEP + j];
    } else {
        int jj = j - KEEP;
        if (jj >= nb) return;
        idx = border_idx[b * BORDER_CAP + jj];
        dst = &border_val[b * BORDER_CAP + jj];
    }
    const int d = (int)(idx >> 13), t = (int)(idx & 8191u);
    const float* xb = x + (size_t)b * CIN * TT;
    const float* wr = Wexp + (size_t)d * CIN;
    float ssum = 0.f;
    for (int k = threadIdx.x; k < CIN; k += 256)
        ssum += xb[(size_t)k * TT + t] * wr[k];
    __shared__ float red[256];
    red[threadIdx.x] = ssum;
    __syncthreads();
    for (int off = 128; off > 0; off >>= 1) {
        if (threadIdx.x < off) red[threadIdx.x] += red[threadIdx.x + off];
        __syncthreads();
    }
    if (threadIdx.x == 0) *dst = red[0] + bexp[d];
}

// ---------------- fill_all: rank borderline (exact) + ALL output writes --------
// grid (128 t-chunks, 4 dense c-chunks + 8 sparse d-chunks, B). Each block
// redundantly ranks the <=256 borderline entries (exact values) and treats
// rank < KEEP-nsure as selected — no separate finalize kernel.
__global__ __launch_bounds__(256) void fill_all(const float* __restrict__ bcon,
                                                const float* __restrict__ Wcon,
                                                const float* __restrict__ sel_val,
                                                const unsigned* __restrict__ sel_idx,
                                                const float* __restrict__ border_val,
                                                const unsigned* __restrict__ border_idx,
                                                const unsigned* __restrict__ counters,
                                                float* __restrict__ out) {
    const int tcb = blockIdx.x;          // 128 chunks of 64 t
    const int yc  = blockIdx.y;          // 0..3 dense, 4..11 sparse
    const int b   = blockIdx.z;
    const int tid = threadIdx.x;
    const int t0 = tcb * 64;

    __shared__ float s_bv[BORDER_CAP];
    __shared__ unsigned s_bi[BORDER_CAP];
    __shared__ unsigned char s_bsel[BORDER_CAP];
    __shared__ float s_v[FILL_CAP];
    __shared__ int s_t[FILL_CAP], s_d[FILL_CAP];
    __shared__ unsigned s_ne;

    const int nsure = (int)counters[4 + b];
    const int nb = (int)counters[8 + b];
    if (tid == 0) s_ne = 0;
    if (tid < nb) {
        s_bv[tid] = border_val[b * BORDER_CAP + tid];
        s_bi[tid] = border_idx[b * BORDER_CAP + tid];
    }
    __syncthreads();
    int krem = KEEP - nsure;
    if (krem < 0) krem = 0;
    if (krem > nb) krem = nb;
    if (tid < nb) {
        float v = s_bv[tid];
        unsigned idx = s_bi[tid];
        int rank = 0;
        for (int j = 0; j < nb; ++j) {
            float vj = s_bv[j];
            unsigned ij = s_bi[j];
            if (vj > v || (vj == v && ij < idx)) rank++;
        }
        s_bsel[tid] = (rank < krem) ? 1 : 0;
    }
    __syncthreads();

    if (yc < 4) {
        const int c0 = yc * 256;
        for (int i = tid; i < nsure; i += 256) {
            unsigned idx = sel_idx[b * KEEP + i];
            int t = (int)(idx & 8191u);
            if (t >= t0 && t < t0 + 64) {
                unsigned p = atomicAdd(&s_ne, 1u);
                if (p < FILL_CAP) {
                    s_v[p] = sel_val[b * KEEP + i];
                    s_t[p] = t - t0;
                    s_d[p] = (int)(idx >> 13);
                }
            }
        }
        for (int j = tid; j < nb; j += 256) {
            if (s_bsel[j]) {
                unsigned idx = s_bi[j];
                int t = (int)(idx & 8191u);
                if (t >= t0 && t < t0 + 64) {
                    unsigned p = atomicAdd(&s_ne, 1u);
                    if (p < FILL_CAP) {
                        s_v[p] = s_bv[j];
                        s_t[p] = t - t0;
                        s_d[p] = (int)(idx >> 13);
                    }
                }
            }
        }
        __syncthreads();
        const int ne = (int)(s_ne < FILL_CAP ? s_ne : FILL_CAP);
        const int lane16 = tid & 15;
        const int cr = tid >> 4;
        for (int it = 0; it < 16; ++it) {
            int c = c0 + it * 16 + cr;
            float bias = bcon[c];
            float v0 = bias, v1 = bias, v2 = bias, v3 = bias;
            for (int j = 0; j < ne; ++j) {
                int tj = s_t[j];
                if ((tj >> 2) == lane16) {
                    float add = s_v[j] * Wcon[(size_t)c * DHI + s_d[j]];
                    int q = tj & 3;
                    if (q == 0) v0 += add;
                    else if (q == 1) v1 += add;
                    else if (q == 2) v2 += add;
                    else v3 += add;
                }
            }
            *(float4*)(&out[(((size_t)(b * CIN + c)) << 13) + t0 + lane16 * 4]) =
                make_float4(v0, v1, v2, v3);
        }
    } else {
        const int d0 = (yc - 4) * 256;
        float* sparse = out + (size_t)OUT_ELEMS + (size_t)b * SPARSE_PER_B;
        for (int i = tid; i < nsure; i += 256) {
            unsigned idx = sel_idx[b * KEEP + i];
            int t = (int)(idx & 8191u), d = (int)(idx >> 13);
            if (t >= t0 && t < t0 + 64 && d >= d0 && d < d0 + 256) {
                unsigned p = atomicAdd(&s_ne, 1u);
                if (p < FILL_CAP) {
                    s_v[p] = sel_val[b * KEEP + i];
                    s_t[p] = t;
                    s_d[p] = d;
                }
            }
        }
        for (int j = tid; j < nb; j += 256) {
            if (s_bsel[j]) {
                unsigned idx = s_bi[j];
                int t = (int)(idx & 8191u), d = (int)(idx >> 13);
                if (t >= t0 && t < t0 + 64 && d >= d0 && d < d0 + 256) {
                    unsigned p = atomicAdd(&s_ne, 1u);
                    if (p < FILL_CAP) {
                        s_v[p] = s_bv[j];
                        s_t[p] = t;
                        s_d[p] = d;
                    }
                }
            }
        }
        __syncthreads();
        const int ne = (int)(s_ne < FILL_CAP ? s_ne : FILL_CAP);
        const int lane16 = tid & 15;
        const int dr = tid >> 4;
        const float4 z = make_float4(0.f, 0.f, 0.f, 0.f);
        for (int it = 0; it < 16; ++it) {
            int d = d0 + it * 16 + dr;
            *(float4*)(&sparse[((size_t)d << 13) + t0 + lane16 * 4]) = z;
        }
        __syncthreads();                 // zeros visible before patch
        if (tid < ne)
            sparse[((size_t)s_d[tid] << 13) + s_t[tid]] = s_v[tid];
    }
}

extern "C" void kernel_launch(void* const* d_in, const int* in_sizes, int n_in,
                              void* d_out, int out_size, void* d_ws, size_t ws_size,
                              hipStream_t stream) {
    const float* x    = (const float*)d_in[0];
    const float* Wexp = (const float*)d_in[1];
    const float* bexp = (const float*)d_in[2];
    const float* Wcon = (const float*)d_in[3];
    const float* bcon = (const float*)d_in[4];
    float* out = (float*)d_out;

    unsigned* counters   = (unsigned*)((char*)d_ws + WS_COUNTERS);
    float*    sel_val    = (float*)((char*)d_ws + WS_SELV);
    unsigned* sel_idx    = (unsigned*)((char*)d_ws + WS_SELI);
    unsigned* border_idx = (unsigned*)((char*)d_ws + WS_BIDX);
    float*    border_val = (float*)((char*)d_ws + WS_BVAL);
    char* cand_base = (char*)d_ws + WS_CAND;
    size_t remain = ws_size - WS_CAND;
    size_t cap_sz = remain / ((size_t)B_SZ * 8);
    int cap = (int)(cap_sz < (size_t)65536 ? cap_sz : (size_t)65536);
    float*    cand_val = (float*)cand_base;
    unsigned* cand_idx = (unsigned*)(cand_base + (size_t)B_SZ * cap * 4);

    // 1) stage bf16-hi A image (4 MB, BK=32-native swizzle)
    convert_A<<<512, 256, 0, stream>>>(Wexp, out, counters);

    // 2) single-product bf16 MFMA GEMM + approx candidate collection
    gemm_fused<<<dim3(64, 16, 4), 256, 0, stream>>>(x, out + AST_F, bexp,
                                                    cand_val, cand_idx, counters, cap);

    // 3) radix kth (approx) + classify into sure / borderline index lists
    select1<<<B_SZ, 256, 0, stream>>>(cand_val, cand_idx, counters,
                                      sel_val, sel_idx, border_idx, cap);

    // 4) exact fp32 recompute of every sure + borderline candidate (parallel)
    recompute<<<dim3(KEEP + BORDER_CAP, B_SZ), 256, 0, stream>>>(
        x, Wexp, bexp, counters, sel_idx, sel_val, border_idx, border_val);

    // 5) single output pass: rank borderline exactly + dense/sparse writes
    fill_all<<<dim3(128, 12, B_SZ), 256, 0, stream>>>(bcon, Wcon, sel_val, sel_idx,
                                                      border_val, border_idx,
                                                      counters, out);
}

// Round 14
// 593.869 us; speedup vs baseline: 1.6124x; 1.0101x over previous
//
#include <hip/hip_runtime.h>

#define B_SZ 4
#define CIN 1024
#define DHI 2048
#define TT 8192
#define KEEP 512
#define OUT_ELEMS (B_SZ*CIN*TT)            // 33554432
#define SPARSE_PER_B (DHI*TT)              // 16777216
#define THRESH 3.0f
#define EPS_SEL 0.04f
#define BORDER_CAP 256
#define FILL_CAP 128

// A staged bf16-hi image lives in the (not-yet-written) sparse region of
// d_out; fill_all (after the gemm) overwrites it with zeros. 4 MB.
#define AST_F ((size_t)OUT_ELEMS)

typedef short bf16x8 __attribute__((ext_vector_type(8)));
typedef float f32x4 __attribute__((ext_vector_type(4)));

__device__ __forceinline__ unsigned short f2bf(float x) {
    unsigned u = __float_as_uint(x);
    return (unsigned short)((u + 0x7fffu + ((u >> 16) & 1u)) >> 16);
}
__device__ __forceinline__ void gload16(const void* g, void* l) {
    __builtin_amdgcn_global_load_lds((const __attribute__((address_space(1))) void*)g,
                                     (__attribute__((address_space(3))) void*)l, 16, 0, 0);
}

// ws: counters[32] | sel_val[4*512] | sel_idx[4*512] | border_idx[4*256] |
//     border_val[4*256] | cand arrays
#define WS_COUNTERS 0
#define WS_SELV 256
#define WS_SELI (256 + 8192)
#define WS_BIDX (256 + 16384)
#define WS_BVAL (256 + 16384 + 4096)
#define WS_CAND (256 + 16384 + 8192)
// counters: [b]=cand cnt, [4+b]=nsure, [8+b]=nborder

// ---------------- convert A: W_exp -> BK=32-native swizzled HI-ONLY chunks -----
// chunk (DB 0..15, KS 0..31): 128 rows(d) x 64B (4 slots x 16B). 64B rows = 2
// rows per 128B bank span -> slot mod 8 = 4(r&1) + P, so the conflict-free
// bijection needs P = L ^ ((r>>1)&3) (XOR the bank-span index, NOT r&3 —
// that collided rows 0/4: R11's 2.5e7 conflicts).
__global__ __launch_bounds__(256) void convert_A(const float* __restrict__ Wexp,
                                                 float* __restrict__ outbuf,
                                                 unsigned* __restrict__ counters) {
    const int cid = blockIdx.x;             // 512 chunks x 8KB = 4MB
    const int DB = cid >> 5, KS = cid & 31;
    char* dst = (char*)(outbuf + AST_F) + (size_t)cid * 8192;
    for (int it = 0; it < 2; ++it) {
        int slot = threadIdx.x + it * 256;  // 0..511
        int r = slot >> 2, P = slot & 3;
        int L = P ^ ((r >> 1) & 3);
        const float* src = Wexp + (size_t)(DB * 128 + r) * CIN + KS * 32 + L * 8;
        unsigned short v[8] __attribute__((aligned(16)));
#pragma unroll
        for (int j = 0; j < 8; ++j) v[j] = f2bf(src[j]);
        *(bf16x8*)(dst + r * 64 + P * 16) = *(const bf16x8*)v;
    }
    if (blockIdx.x == 0 && threadIdx.x < 32) counters[threadIdx.x] = 0u;
}

// ---------------- GEMM: SINGLE bf16 product (Ahi*Bhi), BK=32 -------------------
// 128x128 tile, 4 waves x 64x64. Approximation error sigma ~2.3e-3 (max ~0.013
// over all candidates) — selection correctness restored by EPS_SEL window +
// exact fp32 recompute of all sure+borderline entries (select1/recompute).
__global__ __launch_bounds__(256, 4) void gemm_fused(const float* __restrict__ x,
                                                     const float* __restrict__ stagedA,
                                                     const float* __restrict__ bexp,
                                                     float* __restrict__ cand_val,
                                                     unsigned* __restrict__ cand_idx,
                                                     unsigned* __restrict__ counters,
                                                     int cap) {
    __shared__ char lds[16384];
    __shared__ float s_cv[512];
    __shared__ unsigned s_ci[512];
    __shared__ unsigned s_cnt, s_base;

    const int tid = threadIdx.x;
    const int l = tid & 63, w = tid >> 6;
    const int wm = w >> 1, wn = w & 1;
    const int bx = blockIdx.x, by = blockIdx.y, b = blockIdx.z;

    const char* Achunk0 = (const char*)stagedA + (size_t)(by * 32) * 8192;
    const float* xb = x + (size_t)b * CIN * TT + bx * 128;

    f32x4 acc[4][4];
#pragma unroll
    for (int i = 0; i < 4; ++i)
#pragma unroll
        for (int j = 0; j < 4; ++j) acc[i][j] = (f32x4)0.f;

    char* ldsA = &lds[0];
    char* ldsB = &lds[8192];

    for (int ks = 0; ks < 32; ++ks) {
        const int k0 = ks * 32;
        // A staging: async global->LDS, 2KB per wave (L2-hot staged image)
        {
            const char* gsrcA = Achunk0 + (size_t)ks * 8192 + w * 2048;
            char* ldstA = ldsA + w * 2048;
            gload16(gsrcA + l * 16, (void*)ldstA);
            gload16(gsrcA + 1024 + l * 16, (void*)(ldstA + 1024));
        }
        // B staging: read x fp32 (k-strided, wave-coalesced in t), TRUNCATE to
        // bf16 hi, write swizzled 16B slots (bank-span XOR). 2 tasks/thread.
#pragma unroll
        for (int q = 0; q < 2; ++q) {
            int task = tid + q * 256;            // 0..511
            int t = task & 127, ko = task >> 7;  // ko in 0..3
            const float* src = xb + (size_t)(k0 + ko * 8) * TT + t;
            unsigned short hi[8] __attribute__((aligned(16)));
#pragma unroll
            for (int j = 0; j < 8; ++j)
                hi[j] = (unsigned short)(__float_as_uint(src[(size_t)j * TT]) >> 16);
            int Ph = ko ^ ((t >> 1) & 3);
            *(bf16x8*)(ldsB + t * 64 + Ph * 16) = *(const bf16x8*)hi;
        }
        __syncthreads();

        {
            bf16x8 af[4], bfr[4];
#pragma unroll
            for (int i = 0; i < 4; ++i) {
                int r = wm * 64 + i * 16 + (l & 15);
                int P = (l >> 4) ^ ((r >> 1) & 3);
                af[i] = *(const bf16x8*)(ldsA + r * 64 + P * 16);
            }
#pragma unroll
            for (int j = 0; j < 4; ++j) {
                int r = wn * 64 + j * 16 + (l & 15);
                int P = (l >> 4) ^ ((r >> 1) & 3);
                bfr[j] = *(const bf16x8*)(ldsB + r * 64 + P * 16);
            }
#pragma unroll
            for (int i = 0; i < 4; ++i)
#pragma unroll
                for (int j = 0; j < 4; ++j)
                    acc[i][j] = __builtin_amdgcn_mfma_f32_16x16x32_bf16(af[i], bfr[j], acc[i][j], 0, 0, 0);
        }
        __syncthreads();
    }

    // Epilogue: bias + threshold candidate collection (approx values).
    if (tid == 0) s_cnt = 0;
    __syncthreads();
#pragma unroll
    for (int i = 0; i < 4; ++i)
#pragma unroll
        for (int j = 0; j < 4; ++j)
#pragma unroll
            for (int q = 0; q < 4; ++q) {
                int d = by * 128 + wm * 64 + i * 16 + (l >> 4) * 4 + q;
                int t = bx * 128 + wn * 64 + j * 16 + (l & 15);
                float val = acc[i][j][q] + bexp[d];
                if (val > THRESH) {
                    unsigned p = atomicAdd(&s_cnt, 1u);
                    if (p < 512u) {
                        s_cv[p] = val;
                        s_ci[p] = (unsigned)(d * TT + t);
                    }
                }
            }
    __syncthreads();
    unsigned n = s_cnt < 512u ? s_cnt : 512u;
    if (tid == 0) s_base = atomicAdd(&counters[b], n);
    __syncthreads();
    unsigned base = s_base;
    for (unsigned i = tid; i < n; i += 256u) {
        unsigned pos = base + i;
        if (pos < (unsigned)cap) {
            cand_val[(size_t)b * cap + pos] = s_cv[i];
            cand_idx[(size_t)b * cap + pos] = s_ci[i];
        }
    }
}

// ---------------- select1: radix kth on approx values + classify ---------------
__global__ __launch_bounds__(256) void select1(const float* __restrict__ cand_val,
                                               const unsigned* __restrict__ cand_idx,
                                               unsigned* __restrict__ counters,
                                               float* __restrict__ sel_val,
                                               unsigned* __restrict__ sel_idx,
                                               unsigned* __restrict__ border_idx,
                                               int cap) {
    const int b = blockIdx.x;
    const int tid = threadIdx.x;
    const float* cv = cand_val + (size_t)b * cap;
    const unsigned* ci = cand_idx + (size_t)b * cap;
    unsigned nc = counters[b];
    int n = (int)(nc < (unsigned)cap ? nc : (unsigned)cap);

    __shared__ unsigned hist[256];
    __shared__ unsigned s_sel, s_rem, s_scnt, s_bcnt;

    for (int i = tid; i < KEEP; i += 256) {
        sel_val[b * KEEP + i] = 0.f;
        sel_idx[b * KEEP + i] = 0u;
    }

    unsigned prefix = 0;
    int remaining = KEEP;
    for (int pass = 0; pass < 4; ++pass) {
        int shift = 24 - pass * 8;
        hist[tid] = 0;
        __syncthreads();
        for (int i = tid; i < n; i += 256) {
            unsigned u = __float_as_uint(cv[i]);
            unsigned hb = (pass == 0) ? 0u : (u >> (shift + 8));
            if (hb == prefix) atomicAdd(&hist[(u >> shift) & 255u], 1u);
        }
        __syncthreads();
        if (tid == 0) {
            int rem = remaining;
            unsigned selb = 0;
            for (int byte = 255; byte >= 0; --byte) {
                int c = (int)hist[byte];
                if (c >= rem) { selb = (unsigned)byte; break; }
                rem -= c;
            }
            s_sel = selb;
            s_rem = (unsigned)rem;
        }
        __syncthreads();
        prefix = (prefix << 8) | s_sel;
        remaining = (int)s_rem;
        __syncthreads();
    }

    if (tid == 0) { s_scnt = 0; s_bcnt = 0; }
    __syncthreads();
    const float kth = __uint_as_float(prefix);
    const float hiv = kth + EPS_SEL, lov = kth - EPS_SEL;
    for (int i = tid; i < n; i += 256) {
        float v = cv[i];
        if (v > hiv) {
            unsigned p = atomicAdd(&s_scnt, 1u);
            if (p < (unsigned)KEEP) sel_idx[b * KEEP + p] = ci[i];
        } else if (v >= lov) {
            unsigned q = atomicAdd(&s_bcnt, 1u);
            if (q < BORDER_CAP) border_idx[b * BORDER_CAP + q] = ci[i];
        }
    }
    __syncthreads();
    if (tid == 0) {
        counters[4 + b] = s_scnt < (unsigned)KEEP ? s_scnt : (unsigned)KEEP;
        counters[8 + b] = s_bcnt < BORDER_CAP ? s_bcnt : BORDER_CAP;
    }
}

// ---------------- recompute: exact fp32 dot for every sure + borderline entry --
__global__ __launch_bounds__(256) void recompute(const float* __restrict__ x,
                                                 const float* __restrict__ Wexp,
                                                 const float* __restrict__ bexp,
                                                 const unsigned* __restrict__ counters,
                                                 const unsigned* __restrict__ sel_idx,
                                                 float* __restrict__ sel_val,
                                                 const unsigned* __restrict__ border_idx,
                                                 float* __restrict__ border_val) {
    const int j = blockIdx.x, b = blockIdx.y;
    const int nsure = (int)counters[4 + b];
    const int nb = (int)counters[8 + b];
    unsigned idx;
    float* dst;
    if (j < KEEP) {
        if (j >= nsure) return;
        idx = sel_idx[b * KEEP + j];
        dst = &sel_val[b * KEEP + j];
    } else {
        int jj = j - KEEP;
        if (jj >= nb) return;
        idx = border_idx[b * BORDER_CAP + jj];
        dst = &border_val[b * BORDER_CAP + jj];
    }
    const int d = (int)(idx >> 13), t = (int)(idx & 8191u);
    const float* xb = x + (size_t)b * CIN * TT;
    const float* wr = Wexp + (size_t)d * CIN;
    float ssum = 0.f;
    for (int k = threadIdx.x; k < CIN; k += 256)
        ssum += xb[(size_t)k * TT + t] * wr[k];
    __shared__ float red[256];
    red[threadIdx.x] = ssum;
    __syncthreads();
    for (int off = 128; off > 0; off >>= 1) {
        if (threadIdx.x < off) red[threadIdx.x] += red[threadIdx.x + off];
        __syncthreads();
    }
    if (threadIdx.x == 0) *dst = red[0] + bexp[d];
}

// ---------------- fill_all: rank borderline (exact) + ALL output writes --------
__global__ __launch_bounds__(256) void fill_all(const float* __restrict__ bcon,
                                                const float* __restrict__ Wcon,
                                                const float* __restrict__ sel_val,
                                                const unsigned* __restrict__ sel_idx,
                                                const float* __restrict__ border_val,
                                                const unsigned* __restrict__ border_idx,
                                                const unsigned* __restrict__ counters,
                                                float* __restrict__ out) {
    const int tcb = blockIdx.x;          // 128 chunks of 64 t
    const int yc  = blockIdx.y;          // 0..3 dense, 4..11 sparse
    const int b   = blockIdx.z;
    const int tid = threadIdx.x;
    const int t0 = tcb * 64;

    __shared__ float s_bv[BORDER_CAP];
    __shared__ unsigned s_bi[BORDER_CAP];
    __shared__ unsigned char s_bsel[BORDER_CAP];
    __shared__ float s_v[FILL_CAP];
    __shared__ int s_t[FILL_CAP], s_d[FILL_CAP];
    __shared__ unsigned s_ne;

    const int nsure = (int)counters[4 + b];
    const int nb = (int)counters[8 + b];
    if (tid == 0) s_ne = 0;
    if (tid < nb) {
        s_bv[tid] = border_val[b * BORDER_CAP + tid];
        s_bi[tid] = border_idx[b * BORDER_CAP + tid];
    }
    __syncthreads();
    int krem = KEEP - nsure;
    if (krem < 0) krem = 0;
    if (krem > nb) krem = nb;
    if (tid < nb) {
        float v = s_bv[tid];
        unsigned idx = s_bi[tid];
        int rank = 0;
        for (int j = 0; j < nb; ++j) {
            float vj = s_bv[j];
            unsigned ij = s_bi[j];
            if (vj > v || (vj == v && ij < idx)) rank++;
        }
        s_bsel[tid] = (rank < krem) ? 1 : 0;
    }
    __syncthreads();

    if (yc < 4) {
        const int c0 = yc * 256;
        for (int i = tid; i < nsure; i += 256) {
            unsigned idx = sel_idx[b * KEEP + i];
            int t = (int)(idx & 8191u);
            if (t >= t0 && t < t0 + 64) {
                unsigned p = atomicAdd(&s_ne, 1u);
                if (p < FILL_CAP) {
                    s_v[p] = sel_val[b * KEEP + i];
                    s_t[p] = t - t0;
                    s_d[p] = (int)(idx >> 13);
                }
            }
        }
        for (int j = tid; j < nb; j += 256) {
            if (s_bsel[j]) {
                unsigned idx = s_bi[j];
                int t = (int)(idx & 8191u);
                if (t >= t0 && t < t0 + 64) {
                    unsigned p = atomicAdd(&s_ne, 1u);
                    if (p < FILL_CAP) {
                        s_v[p] = s_bv[j];
                        s_t[p] = t - t0;
                        s_d[p] = (int)(idx >> 13);
                    }
                }
            }
        }
        __syncthreads();
        const int ne = (int)(s_ne < FILL_CAP ? s_ne : FILL_CAP);
        const int lane16 = tid & 15;
        const int cr = tid >> 4;
        for (int it = 0; it < 16; ++it) {
            int c = c0 + it * 16 + cr;
            float bias = bcon[c];
            float v0 = bias, v1 = bias, v2 = bias, v3 = bias;
            for (int j = 0; j < ne; ++j) {
                int tj = s_t[j];
                if ((tj >> 2) == lane16) {
                    float add = s_v[j] * Wcon[(size_t)c * DHI + s_d[j]];
                    int q = tj & 3;
                    if (q == 0) v0 += add;
                    else if (q == 1) v1 += add;
                    else if (q == 2) v2 += add;
                    else v3 += add;
                }
            }
            *(float4*)(&out[(((size_t)(b * CIN + c)) << 13) + t0 + lane16 * 4]) =
                make_float4(v0, v1, v2, v3);
        }
    } else {
        const int d0 = (yc - 4) * 256;
        float* sparse = out + (size_t)OUT_ELEMS + (size_t)b * SPARSE_PER_B;
        for (int i = tid; i < nsure; i += 256) {
            unsigned idx = sel_idx[b * KEEP + i];
            int t = (int)(idx & 8191u), d = (int)(idx >> 13);
            if (t >= t0 && t < t0 + 64 && d >= d0 && d < d0 + 256) {
                unsigned p = atomicAdd(&s_ne, 1u);
                if (p < FILL_CAP) {
                    s_v[p] = sel_val[b * KEEP + i];
                    s_t[p] = t;
                    s_d[p] = d;
                }
            }
        }
        for (int j = tid; j < nb; j += 256) {
            if (s_bsel[j]) {
                unsigned idx = s_bi[j];
                int t = (int)(idx & 8191u), d = (int)(idx >> 13);
                if (t >= t0 && t < t0 + 64 && d >= d0 && d < d0 + 256) {
                    unsigned p = atomicAdd(&s_ne, 1u);
                    if (p < FILL_CAP) {
                        s_v[p] = s_bv[j];
                        s_t[p] = t;
                        s_d[p] = d;
                    }
                }
            }
        }
        __syncthreads();
        const int ne = (int)(s_ne < FILL_CAP ? s_ne : FILL_CAP);
        const int lane16 = tid & 15;
        const int dr = tid >> 4;
        const float4 z = make_float4(0.f, 0.f, 0.f, 0.f);
        for (int it = 0; it < 16; ++it) {
            int d = d0 + it * 16 + dr;
            *(float4*)(&sparse[((size_t)d << 13) + t0 + lane16 * 4]) = z;
        }
        __syncthreads();                 // zeros visible before patch
        if (tid < ne)
            sparse[((size_t)s_d[tid] << 13) + s_t[tid]] = s_v[tid];
    }
}

extern "C" void kernel_launch(void* const* d_in, const int* in_sizes, int n_in,
                              void* d_out, int out_size, void* d_ws, size_t ws_size,
                              hipStream_t stream) {
    const float* x    = (const float*)d_in[0];
    const float* Wexp = (const float*)d_in[1];
    const float* bexp = (const float*)d_in[2];
    const float* Wcon = (const float*)d_in[3];
    const float* bcon = (const float*)d_in[4];
    float* out = (float*)d_out;

    unsigned* counters   = (unsigned*)((char*)d_ws + WS_COUNTERS);
    float*    sel_val    = (float*)((char*)d_ws + WS_SELV);
    unsigned* sel_idx    = (unsigned*)((char*)d_ws + WS_SELI);
    unsigned* border_idx = (unsigned*)((char*)d_ws + WS_BIDX);
    float*    border_val = (float*)((char*)d_ws + WS_BVAL);
    char* cand_base = (char*)d_ws + WS_CAND;
    size_t remain = ws_size - WS_CAND;
    size_t cap_sz = remain / ((size_t)B_SZ * 8);
    int cap = (int)(cap_sz < (size_t)65536 ? cap_sz : (size_t)65536);
    float*    cand_val = (float*)cand_base;
    unsigned* cand_idx = (unsigned*)(cand_base + (size_t)B_SZ * cap * 4);

    // 1) stage bf16-hi A image (4 MB, BK=32-native bank-span swizzle)
    convert_A<<<512, 256, 0, stream>>>(Wexp, out, counters);

    // 2) single-product bf16 MFMA GEMM + approx candidate collection
    gemm_fused<<<dim3(64, 16, 4), 256, 0, stream>>>(x, out + AST_F, bexp,
                                                    cand_val, cand_idx, counters, cap);

    // 3) radix kth (approx) + classify into sure / borderline index lists
    select1<<<B_SZ, 256, 0, stream>>>(cand_val, cand_idx, counters,
                                      sel_val, sel_idx, border_idx, cap);

    // 4) exact fp32 recompute of every sure + borderline candidate (parallel)
    recompute<<<dim3(KEEP + BORDER_CAP, B_SZ), 256, 0, stream>>>(
        x, Wexp, bexp, counters, sel_idx, sel_val, border_idx, border_val);

    // 5) single output pass: rank borderline exactly + dense/sparse writes
    fill_all<<<dim3(128, 12, B_SZ), 256, 0, stream>>>(bcon, Wcon, sel_val, sel_idx,
                                                      border_val, border_idx,
                                                      counters, out);
}

// Round 15
// 538.502 us; speedup vs baseline: 1.7782x; 1.1028x over previous
//
#include <hip/hip_runtime.h>

#define B_SZ 4
#define CIN 1024
#define DHI 2048
#define TT 8192
#define KEEP 512
#define OUT_ELEMS (B_SZ*CIN*TT)            // 33554432
#define SPARSE_PER_B (DHI*TT)              // 16777216
#define THRESH 3.0f
#define EPS_SEL 0.04f
#define BORDER_CAP 256
#define FILL_CAP 128

// A staged bf16-hi image lives in the (not-yet-written) sparse region of
// d_out; fill_all (after the gemm) overwrites it with zeros. 4 MB.
#define AST_F ((size_t)OUT_ELEMS)

typedef short bf16x8 __attribute__((ext_vector_type(8)));
typedef float f32x4 __attribute__((ext_vector_type(4)));

__device__ __forceinline__ unsigned short f2bf(float x) {
    unsigned u = __float_as_uint(x);
    return (unsigned short)((u + 0x7fffu + ((u >> 16) & 1u)) >> 16);
}
__device__ __forceinline__ void gload16(const void* g, void* l) {
    __builtin_amdgcn_global_load_lds((const __attribute__((address_space(1))) void*)g,
                                     (__attribute__((address_space(3))) void*)l, 16, 0, 0);
}

// ws: counters[32] | sel_val[4*512] | sel_idx[4*512] | border_idx[4*256] |
//     border_val[4*256] | cand arrays
#define WS_COUNTERS 0
#define WS_SELV 256
#define WS_SELI (256 + 8192)
#define WS_BIDX (256 + 16384)
#define WS_BVAL (256 + 16384 + 4096)
#define WS_CAND (256 + 16384 + 8192)
// counters: [b]=cand cnt, [4+b]=nsure, [8+b]=nborder

// ---------------- convert A: W_exp -> BK=32-native swizzled HI-ONLY chunks -----
// chunk (DB 0..15, KS 0..31): 128 rows(d) x 64B (4 slots x 16B). 64B rows = 2
// rows per 128B bank span -> P = L ^ ((r>>1)&3) (bank-span bijection; verified
// conflict-free R14: SQ_LDS_BANK_CONFLICT = 0).
__global__ __launch_bounds__(256) void convert_A(const float* __restrict__ Wexp,
                                                 float* __restrict__ outbuf,
                                                 unsigned* __restrict__ counters) {
    const int cid = blockIdx.x;             // 512 chunks x 8KB = 4MB
    const int DB = cid >> 5, KS = cid & 31;
    char* dst = (char*)(outbuf + AST_F) + (size_t)cid * 8192;
    for (int it = 0; it < 2; ++it) {
        int slot = threadIdx.x + it * 256;  // 0..511
        int r = slot >> 2, P = slot & 3;
        int L = P ^ ((r >> 1) & 3);
        const float* src = Wexp + (size_t)(DB * 128 + r) * CIN + KS * 32 + L * 8;
        unsigned short v[8] __attribute__((aligned(16)));
#pragma unroll
        for (int j = 0; j < 8; ++j) v[j] = f2bf(src[j]);
        *(bf16x8*)(dst + r * 64 + P * 16) = *(const bf16x8*)v;
    }
    if (blockIdx.x == 0 && threadIdx.x < 32) counters[threadIdx.x] = 0u;
}

// ---------------- GEMM: single bf16 product, B register prefetch pipeline ------
// 128x128 tile, 4 waves x 64x64, BK=32. Per K-step: A gload_lds (pinned oldest
// by sched_barrier) | convert prev breg + ds_write | issue next 16 B loads |
// vmcnt(16) (waits ONLY the 2 A gloads; B prefetch flies across the barrier,
// hiding its ~600-900cyc latency under MFMA + next convert) | s_barrier | MFMA
// | s_barrier. R8's version of this died on VGPR (152, breg[32], 3-product);
// single-product breg[16] keeps VGPR in the same occupancy band as R14.
// Epilogue s_cv/s_ci overlaid on staging LDS (safe after final barrier).
__global__ __launch_bounds__(256, 4) void gemm_fused(const float* __restrict__ x,
                                                     const float* __restrict__ stagedA,
                                                     const float* __restrict__ bexp,
                                                     float* __restrict__ cand_val,
                                                     unsigned* __restrict__ cand_idx,
                                                     unsigned* __restrict__ counters,
                                                     int cap) {
    __shared__ char lds[16896];

    const int tid = threadIdx.x;
    const int l = tid & 63, w = tid >> 6;
    const int wm = w >> 1, wn = w & 1;
    const int bx = blockIdx.x, by = blockIdx.y, b = blockIdx.z;

    const char* Achunk0 = (const char*)stagedA + (size_t)(by * 32) * 8192;
    const float* xb = x + (size_t)b * CIN * TT + bx * 128;

    f32x4 acc[4][4];
#pragma unroll
    for (int i = 0; i < 4; ++i)
#pragma unroll
        for (int j = 0; j < 4; ++j) acc[i][j] = (f32x4)0.f;

    char* ldsA = &lds[0];
    char* ldsB = &lds[8192];

    const int t_ = tid & 127;                 // staging column (fixed per thread)
    // task q: t = t_, ko = (tid>>7) + 2q  — matches task = tid + q*256 mapping
    const int ko0 = tid >> 7;

    float breg[16];
    // prologue: load B(ks=0) into regs
#pragma unroll
    for (int q = 0; q < 2; ++q) {
        const float* src = xb + (size_t)((ko0 + 2 * q) * 8) * TT + t_;
#pragma unroll
        for (int j = 0; j < 8; ++j) breg[q * 8 + j] = src[(size_t)j * TT];
    }

    for (int ks = 0; ks < 32; ++ks) {
        // A staging for current ks (issue first -> oldest vm ops)
        {
            const char* gsrcA = Achunk0 + (size_t)ks * 8192 + w * 2048;
            char* ldstA = ldsA + w * 2048;
            gload16(gsrcA + l * 16, (void*)ldstA);
            gload16(gsrcA + 1024 + l * 16, (void*)(ldstA + 1024));
        }
        __builtin_amdgcn_sched_barrier(0);   // pin A gloads as the oldest vm ops

        // convert current breg -> bf16 hi, write swizzled 16B slots
#pragma unroll
        for (int q = 0; q < 2; ++q) {
            int ko = ko0 + 2 * q;
            unsigned short hi[8] __attribute__((aligned(16)));
#pragma unroll
            for (int j = 0; j < 8; ++j)
                hi[j] = (unsigned short)(__float_as_uint(breg[q * 8 + j]) >> 16);
            int Ph = ko ^ ((t_ >> 1) & 3);
            *(bf16x8*)(ldsB + t_ * 64 + Ph * 16) = *(const bf16x8*)hi;
        }
        // issue next K-step's 16 B loads (they stay in flight across the barrier)
        if (ks < 31) {
#pragma unroll
            for (int q = 0; q < 2; ++q) {
                const float* src = xb + (size_t)((ks + 1) * 32 + (ko0 + 2 * q) * 8) * TT + t_;
#pragma unroll
                for (int j = 0; j < 8; ++j) breg[q * 8 + j] = src[(size_t)j * TT];
            }
            __builtin_amdgcn_sched_barrier(0);
            // wait: 2 A gloads (oldest) done + ds_writes done; 16 B loads in flight
            asm volatile("s_waitcnt vmcnt(16) lgkmcnt(0)" ::: "memory");
        } else {
            asm volatile("s_waitcnt vmcnt(0) lgkmcnt(0)" ::: "memory");
        }
        __builtin_amdgcn_s_barrier();

        {
            bf16x8 af[4], bfr[4];
#pragma unroll
            for (int i = 0; i < 4; ++i) {
                int r = wm * 64 + i * 16 + (l & 15);
                int P = (l >> 4) ^ ((r >> 1) & 3);
                af[i] = *(const bf16x8*)(ldsA + r * 64 + P * 16);
            }
#pragma unroll
            for (int j = 0; j < 4; ++j) {
                int r = wn * 64 + j * 16 + (l & 15);
                int P = (l >> 4) ^ ((r >> 1) & 3);
                bfr[j] = *(const bf16x8*)(ldsB + r * 64 + P * 16);
            }
#pragma unroll
            for (int i = 0; i < 4; ++i)
#pragma unroll
                for (int j = 0; j < 4; ++j)
                    acc[i][j] = __builtin_amdgcn_mfma_f32_16x16x32_bf16(af[i], bfr[j], acc[i][j], 0, 0, 0);
        }
        __builtin_amdgcn_s_barrier();        // all waves done reading before next writes
    }

    // Epilogue: bias + threshold candidate collection (approx values).
    // LDS overlay: staging buffers dead after final barrier.
    float* s_cv = (float*)&lds[0];
    unsigned* s_ci = (unsigned*)&lds[2048 * 2];      // wrong offset guard below
    s_ci = (unsigned*)&lds[2048];
    unsigned* ps_cnt = (unsigned*)&lds[4096];
    unsigned* ps_base = (unsigned*)&lds[4100];
    // NOTE: s_cv = lds[0..2047] (512 f32), s_ci = lds[2048..4095] (512 u32)
    if (tid == 0) *ps_cnt = 0;
    __syncthreads();
#pragma unroll
    for (int i = 0; i < 4; ++i)
#pragma unroll
        for (int j = 0; j < 4; ++j)
#pragma unroll
            for (int q = 0; q < 4; ++q) {
                int d = by * 128 + wm * 64 + i * 16 + (l >> 4) * 4 + q;
                int t = bx * 128 + wn * 64 + j * 16 + (l & 15);
                float val = acc[i][j][q] + bexp[d];
                if (val > THRESH) {
                    unsigned p = atomicAdd(ps_cnt, 1u);
                    if (p < 512u) {
                        s_cv[p] = val;
                        s_ci[p] = (unsigned)(d * TT + t);
                    }
                }
            }
    __syncthreads();
    unsigned n = *ps_cnt < 512u ? *ps_cnt : 512u;
    if (tid == 0) *ps_base = atomicAdd(&counters[b], n);
    __syncthreads();
    unsigned base = *ps_base;
    for (unsigned i = tid; i < n; i += 256u) {
        unsigned pos = base + i;
        if (pos < (unsigned)cap) {
            cand_val[(size_t)b * cap + pos] = s_cv[i];
            cand_idx[(size_t)b * cap + pos] = s_ci[i];
        }
    }
}

// ---------------- select1: radix kth on approx values + classify ---------------
__global__ __launch_bounds__(256) void select1(const float* __restrict__ cand_val,
                                               const unsigned* __restrict__ cand_idx,
                                               unsigned* __restrict__ counters,
                                               float* __restrict__ sel_val,
                                               unsigned* __restrict__ sel_idx,
                                               unsigned* __restrict__ border_idx,
                                               int cap) {
    const int b = blockIdx.x;
    const int tid = threadIdx.x;
    const float* cv = cand_val + (size_t)b * cap;
    const unsigned* ci = cand_idx + (size_t)b * cap;
    unsigned nc = counters[b];
    int n = (int)(nc < (unsigned)cap ? nc : (unsigned)cap);

    __shared__ unsigned hist[256];
    __shared__ unsigned s_sel, s_rem, s_scnt, s_bcnt;

    for (int i = tid; i < KEEP; i += 256) {
        sel_val[b * KEEP + i] = 0.f;
        sel_idx[b * KEEP + i] = 0u;
    }

    unsigned prefix = 0;
    int remaining = KEEP;
    for (int pass = 0; pass < 4; ++pass) {
        int shift = 24 - pass * 8;
        hist[tid] = 0;
        __syncthreads();
        for (int i = tid; i < n; i += 256) {
            unsigned u = __float_as_uint(cv[i]);
            unsigned hb = (pass == 0) ? 0u : (u >> (shift + 8));
            if (hb == prefix) atomicAdd(&hist[(u >> shift) & 255u], 1u);
        }
        __syncthreads();
        if (tid == 0) {
            int rem = remaining;
            unsigned selb = 0;
            for (int byte = 255; byte >= 0; --byte) {
                int c = (int)hist[byte];
                if (c >= rem) { selb = (unsigned)byte; break; }
                rem -= c;
            }
            s_sel = selb;
            s_rem = (unsigned)rem;
        }
        __syncthreads();
        prefix = (prefix << 8) | s_sel;
        remaining = (int)s_rem;
        __syncthreads();
    }

    if (tid == 0) { s_scnt = 0; s_bcnt = 0; }
    __syncthreads();
    const float kth = __uint_as_float(prefix);
    const float hiv = kth + EPS_SEL, lov = kth - EPS_SEL;
    for (int i = tid; i < n; i += 256) {
        float v = cv[i];
        if (v > hiv) {
            unsigned p = atomicAdd(&s_scnt, 1u);
            if (p < (unsigned)KEEP) sel_idx[b * KEEP + p] = ci[i];
        } else if (v >= lov) {
            unsigned q = atomicAdd(&s_bcnt, 1u);
            if (q < BORDER_CAP) border_idx[b * BORDER_CAP + q] = ci[i];
        }
    }
    __syncthreads();
    if (tid == 0) {
        counters[4 + b] = s_scnt < (unsigned)KEEP ? s_scnt : (unsigned)KEEP;
        counters[8 + b] = s_bcnt < BORDER_CAP ? s_bcnt : BORDER_CAP;
    }
}

// ---------------- recompute: exact fp32 dot for every sure + borderline entry --
__global__ __launch_bounds__(256) void recompute(const float* __restrict__ x,
                                                 const float* __restrict__ Wexp,
                                                 const float* __restrict__ bexp,
                                                 const unsigned* __restrict__ counters,
                                                 const unsigned* __restrict__ sel_idx,
                                                 float* __restrict__ sel_val,
                                                 const unsigned* __restrict__ border_idx,
                                                 float* __restrict__ border_val) {
    const int j = blockIdx.x, b = blockIdx.y;
    const int nsure = (int)counters[4 + b];
    const int nb = (int)counters[8 + b];
    unsigned idx;
    float* dst;
    if (j < KEEP) {
        if (j >= nsure) return;
        idx = sel_idx[b * KEEP + j];
        dst = &sel_val[b * KEEP + j];
    } else {
        int jj = j - KEEP;
        if (jj >= nb) return;
        idx = border_idx[b * BORDER_CAP + jj];
        dst = &border_val[b * BORDER_CAP + jj];
    }
    const int d = (int)(idx >> 13), t = (int)(idx & 8191u);
    const float* xb = x + (size_t)b * CIN * TT;
    const float* wr = Wexp + (size_t)d * CIN;
    float ssum = 0.f;
    for (int k = threadIdx.x; k < CIN; k += 256)
        ssum += xb[(size_t)k * TT + t] * wr[k];
    __shared__ float red[256];
    red[threadIdx.x] = ssum;
    __syncthreads();
    for (int off = 128; off > 0; off >>= 1) {
        if (threadIdx.x < off) red[threadIdx.x] += red[threadIdx.x + off];
        __syncthreads();
    }
    if (threadIdx.x == 0) *dst = red[0] + bexp[d];
}

// ---------------- fill_all: rank borderline (exact) + ALL output writes --------
__global__ __launch_bounds__(256) void fill_all(const float* __restrict__ bcon,
                                                const float* __restrict__ Wcon,
                                                const float* __restrict__ sel_val,
                                                const unsigned* __restrict__ sel_idx,
                                                const float* __restrict__ border_val,
                                                const unsigned* __restrict__ border_idx,
                                                const unsigned* __restrict__ counters,
                                                float* __restrict__ out) {
    const int tcb = blockIdx.x;          // 128 chunks of 64 t
    const int yc  = blockIdx.y;          // 0..3 dense, 4..11 sparse
    const int b   = blockIdx.z;
    const int tid = threadIdx.x;
    const int t0 = tcb * 64;

    __shared__ float s_bv[BORDER_CAP];
    __shared__ unsigned s_bi[BORDER_CAP];
    __shared__ unsigned char s_bsel[BORDER_CAP];
    __shared__ float s_v[FILL_CAP];
    __shared__ int s_t[FILL_CAP], s_d[FILL_CAP];
    __shared__ unsigned s_ne;

    const int nsure = (int)counters[4 + b];
    const int nb = (int)counters[8 + b];
    if (tid == 0) s_ne = 0;
    if (tid < nb) {
        s_bv[tid] = border_val[b * BORDER_CAP + tid];
        s_bi[tid] = border_idx[b * BORDER_CAP + tid];
    }
    __syncthreads();
    int krem = KEEP - nsure;
    if (krem < 0) krem = 0;
    if (krem > nb) krem = nb;
    if (tid < nb) {
        float v = s_bv[tid];
        unsigned idx = s_bi[tid];
        int rank = 0;
        for (int j = 0; j < nb; ++j) {
            float vj = s_bv[j];
            unsigned ij = s_bi[j];
            if (vj > v || (vj == v && ij < idx)) rank++;
        }
        s_bsel[tid] = (rank < krem) ? 1 : 0;
    }
    __syncthreads();

    if (yc < 4) {
        const int c0 = yc * 256;
        for (int i = tid; i < nsure; i += 256) {
            unsigned idx = sel_idx[b * KEEP + i];
            int t = (int)(idx & 8191u);
            if (t >= t0 && t < t0 + 64) {
                unsigned p = atomicAdd(&s_ne, 1u);
                if (p < FILL_CAP) {
                    s_v[p] = sel_val[b * KEEP + i];
                    s_t[p] = t - t0;
                    s_d[p] = (int)(idx >> 13);
                }
            }
        }
        for (int j = tid; j < nb; j += 256) {
            if (s_bsel[j]) {
                unsigned idx = s_bi[j];
                int t = (int)(idx & 8191u);
                if (t >= t0 && t < t0 + 64) {
                    unsigned p = atomicAdd(&s_ne, 1u);
                    if (p < FILL_CAP) {
                        s_v[p] = s_bv[j];
                        s_t[p] = t - t0;
                        s_d[p] = (int)(idx >> 13);
                    }
                }
            }
        }
        __syncthreads();
        const int ne = (int)(s_ne < FILL_CAP ? s_ne : FILL_CAP);
        const int lane16 = tid & 15;
        const int cr = tid >> 4;
        for (int it = 0; it < 16; ++it) {
            int c = c0 + it * 16 + cr;
            float bias = bcon[c];
            float v0 = bias, v1 = bias, v2 = bias, v3 = bias;
            for (int j = 0; j < ne; ++j) {
                int tj = s_t[j];
                if ((tj >> 2) == lane16) {
                    float add = s_v[j] * Wcon[(size_t)c * DHI + s_d[j]];
                    int q = tj & 3;
                    if (q == 0) v0 += add;
                    else if (q == 1) v1 += add;
                    else if (q == 2) v2 += add;
                    else v3 += add;
                }
            }
            *(float4*)(&out[(((size_t)(b * CIN + c)) << 13) + t0 + lane16 * 4]) =
                make_float4(v0, v1, v2, v3);
        }
    } else {
        const int d0 = (yc - 4) * 256;
        float* sparse = out + (size_t)OUT_ELEMS + (size_t)b * SPARSE_PER_B;
        for (int i = tid; i < nsure; i += 256) {
            unsigned idx = sel_idx[b * KEEP + i];
            int t = (int)(idx & 8191u), d = (int)(idx >> 13);
            if (t >= t0 && t < t0 + 64 && d >= d0 && d < d0 + 256) {
                unsigned p = atomicAdd(&s_ne, 1u);
                if (p < FILL_CAP) {
                    s_v[p] = sel_val[b * KEEP + i];
                    s_t[p] = t;
                    s_d[p] = d;
                }
            }
        }
        for (int j = tid; j < nb; j += 256) {
            if (s_bsel[j]) {
                unsigned idx = s_bi[j];
                int t = (int)(idx & 8191u), d = (int)(idx >> 13);
                if (t >= t0 && t < t0 + 64 && d >= d0 && d < d0 + 256) {
                    unsigned p = atomicAdd(&s_ne, 1u);
                    if (p < FILL_CAP) {
                        s_v[p] = s_bv[j];
                        s_t[p] = t;
                        s_d[p] = d;
                    }
                }
            }
        }
        __syncthreads();
        const int ne = (int)(s_ne < FILL_CAP ? s_ne : FILL_CAP);
        const int lane16 = tid & 15;
        const int dr = tid >> 4;
        const float4 z = make_float4(0.f, 0.f, 0.f, 0.f);
        for (int it = 0; it < 16; ++it) {
            int d = d0 + it * 16 + dr;
            *(float4*)(&sparse[((size_t)d << 13) + t0 + lane16 * 4]) = z;
        }
        __syncthreads();                 // zeros visible before patch
        if (tid < ne)
            sparse[((size_t)s_d[tid] << 13) + s_t[tid]] = s_v[tid];
    }
}

extern "C" void kernel_launch(void* const* d_in, const int* in_sizes, int n_in,
                              void* d_out, int out_size, void* d_ws, size_t ws_size,
                              hipStream_t stream) {
    const float* x    = (const float*)d_in[0];
    const float* Wexp = (const float*)d_in[1];
    const float* bexp = (const float*)d_in[2];
    const float* Wcon = (const float*)d_in[3];
    const float* bcon = (const float*)d_in[4];
    float* out = (float*)d_out;

    unsigned* counters   = (unsigned*)((char*)d_ws + WS_COUNTERS);
    float*    sel_val    = (float*)((char*)d_ws + WS_SELV);
    unsigned* sel_idx    = (unsigned*)((char*)d_ws + WS_SELI);
    unsigned* border_idx = (unsigned*)((char*)d_ws + WS_BIDX);
    float*    border_val = (float*)((char*)d_ws + WS_BVAL);
    char* cand_base = (char*)d_ws + WS_CAND;
    size_t remain = ws_size - WS_CAND;
    size_t cap_sz = remain / ((size_t)B_SZ * 8);
    int cap = (int)(cap_sz < (size_t)65536 ? cap_sz : (size_t)65536);
    float*    cand_val = (float*)cand_base;
    unsigned* cand_idx = (unsigned*)(cand_base + (size_t)B_SZ * cap * 4);

    // 1) stage bf16-hi A image (4 MB, BK=32-native bank-span swizzle)
    convert_A<<<512, 256, 0, stream>>>(Wexp, out, counters);

    // 2) single-product bf16 MFMA GEMM, B reg-prefetch pipeline + candidates
    gemm_fused<<<dim3(64, 16, 4), 256, 0, stream>>>(x, out + AST_F, bexp,
                                                    cand_val, cand_idx, counters, cap);

    // 3) radix kth (approx) + classify into sure / borderline index lists
    select1<<<B_SZ, 256, 0, stream>>>(cand_val, cand_idx, counters,
                                      sel_val, sel_idx, border_idx, cap);

    // 4) exact fp32 recompute of every sure + borderline candidate (parallel)
    recompute<<<dim3(KEEP + BORDER_CAP, B_SZ), 256, 0, stream>>>(
        x, Wexp, bexp, counters, sel_idx, sel_val, border_idx, border_val);

    // 5) single output pass: rank borderline exactly + dense/sparse writes
    fill_all<<<dim3(128, 12, B_SZ), 256, 0, stream>>>(bcon, Wcon, sel_val, sel_idx,
                                                      border_val, border_idx,
                                                      counters, out);
}